// Round 12
// baseline (847.733 us; speedup 1.0000x reference)
//
#include <hip/hip_runtime.h>
#include <hip/hip_bf16.h>
#include <math.h>

#define HIDDEN 4096
#define NH 32
#define NKV 8
#define HD 128
#define S_LEN 2048
#define BATCH 2
#define MROWS (BATCH * S_LEN)  // 4096
#define QKVW 6144              // fused q|k|v row width

typedef __attribute__((ext_vector_type(8))) __bf16 bf16x8;
typedef __attribute__((ext_vector_type(4))) float f32x4;

__device__ __forceinline__ f32x4 mfma16(bf16x8 a, bf16x8 b, f32x4 c) {
  return __builtin_amdgcn_mfma_f32_16x16x32_bf16(a, b, c, 0, 0, 0);
}

// async global->LDS, 16B/lane; LDS dest = wave-uniform base, HW adds lane*16.
__device__ __forceinline__ void gload16(const __bf16* g, const __bf16* l) {
  __builtin_amdgcn_global_load_lds(
      (const __attribute__((address_space(1))) void*)g,
      (__attribute__((address_space(3))) void*)l, 16, 0, 0);
}

#define SBAR()                          \
  do {                                  \
    __builtin_amdgcn_sched_barrier(0);  \
    __builtin_amdgcn_s_barrier();       \
    __builtin_amdgcn_sched_barrier(0);  \
  } while (0)

#define VMCNT8()                                              \
  do {                                                        \
    __builtin_amdgcn_sched_barrier(0);                        \
    asm volatile("s_waitcnt vmcnt(8)" ::: "memory");          \
  } while (0)

#define VMCNT6()                                              \
  do {                                                        \
    __builtin_amdgcn_sched_barrier(0);                        \
    asm volatile("s_waitcnt vmcnt(6)" ::: "memory");          \
  } while (0)

// ---------------------------------------------------------------------------
// fp32 -> bf16 elementwise convert (vectorized)
// ---------------------------------------------------------------------------
__global__ __launch_bounds__(256) void cvt_kernel(const float* __restrict__ in,
                                                  __bf16* __restrict__ out, int n) {
  int i = (blockIdx.x * 256 + threadIdx.x) * 8;
  if (i >= n) return;
  float4 a = *reinterpret_cast<const float4*>(in + i);
  float4 b = *reinterpret_cast<const float4*>(in + i + 4);
  bf16x8 t;
  t[0] = (__bf16)a.x; t[1] = (__bf16)a.y; t[2] = (__bf16)a.z; t[3] = (__bf16)a.w;
  t[4] = (__bf16)b.x; t[5] = (__bf16)b.y; t[6] = (__bf16)b.z; t[7] = (__bf16)b.w;
  *reinterpret_cast<bf16x8*>(out + i) = t;
}

// ---------------------------------------------------------------------------
// Fused weight transpose+convert: z=0 Wq (4096 cols), z=1 Wk, z=2 Wv (1024).
// ---------------------------------------------------------------------------
__global__ __launch_bounds__(256) void tcvt3_kernel(const float* __restrict__ Wq,
                                                    const float* __restrict__ Wk,
                                                    const float* __restrict__ Wv,
                                                    __bf16* __restrict__ Wt) {
  __shared__ float t[32][33];
  int z = blockIdx.z;
  const float* in;
  __bf16* out;
  int C;
  if (z == 0)      { in = Wq; out = Wt;                         C = 4096; }
  else if (z == 1) { in = Wk; out = Wt + (size_t)4096 * 4096;   C = 1024; }
  else             { in = Wv; out = Wt + (size_t)5120 * 4096;   C = 1024; }
  if ((int)blockIdx.x * 32 >= C) return;
  int tx = threadIdx.x, ty = threadIdx.y;
  int r0 = blockIdx.y * 32, c0 = blockIdx.x * 32;
#pragma unroll
  for (int i = 0; i < 4; i++)
    t[ty + i * 8][tx] = in[(size_t)(r0 + ty + i * 8) * C + c0 + tx];
  __syncthreads();
#pragma unroll
  for (int i = 0; i < 4; i++)
    out[(size_t)(c0 + ty + i * 8) * 4096 + r0 + tx] = (__bf16)t[tx][ty + i * 8];
}

// single transpose for Wo
__global__ __launch_bounds__(256) void tcvt_f32(const float* __restrict__ in,
                                                __bf16* __restrict__ out,
                                                int R, int C) {
  __shared__ float t[32][33];
  int tx = threadIdx.x, ty = threadIdx.y;
  int r0 = blockIdx.y * 32, c0 = blockIdx.x * 32;
#pragma unroll
  for (int i = 0; i < 4; i++)
    t[ty + i * 8][tx] = in[(size_t)(r0 + ty + i * 8) * C + c0 + tx];
  __syncthreads();
#pragma unroll
  for (int i = 0; i < 4; i++)
    out[(size_t)(c0 + ty + i * 8) * R + r0 + tx] = (__bf16)t[tx][ty + i * 8];
}

// ---------------------------------------------------------------------------
// V transpose: qkv -> vt [B*NKV][HD][S], with pair-interleave permutation
// pi(16a+r) = 32*(a>>1) + 2r + (a&1) applied WITHIN each 64-kv tile.
// Writes stay in the same 64B segment -> coalescing unchanged. attn's
// in-register P packing uses the same pi so PV contracts consistently.
// ---------------------------------------------------------------------------
__global__ __launch_bounds__(256) void tvt_kernel(const __bf16* __restrict__ qkv,
                                                  __bf16* __restrict__ vt) {
  __shared__ __bf16 t[32][33];
  int tx = threadIdx.x, ty = threadIdx.y;
  int z = blockIdx.z;
  int b = z >> 3, kvh = z & 7;
  int kv0 = blockIdx.y * 32, d0 = blockIdx.x * 32;
#pragma unroll
  for (int i = 0; i < 4; i++)
    t[ty + i * 8][tx] =
        qkv[(size_t)(b * S_LEN + kv0 + ty + i * 8) * QKVW + 5120 + kvh * HD + d0 + tx];
  __syncthreads();
  int cperm = kv0 + 2 * (tx & 15) + (tx >> 4);
#pragma unroll
  for (int i = 0; i < 4; i++)
    vt[((size_t)z * HD + d0 + ty + i * 8) * S_LEN + cperm] = t[tx][ty + i * 8];
}

// ---------------------------------------------------------------------------
// 256x256 GEMM, deep-pipelined (R11 version, unchanged).
// ---------------------------------------------------------------------------
template<typename CT>
__global__ __launch_bounds__(512, 2) void gemm256(const __bf16* __restrict__ A,
                                                  const __bf16* __restrict__ Bt,
                                                  CT* __restrict__ C,
                                                  int K, int ldc, int nbx) {
  __shared__ char lds[131072];
  const int tid = threadIdx.x;
  const int l = tid & 63, w = tid >> 6;
  const int lrow = l & 15, lg = l >> 4;
  const int sw = (lrow & 7) << 4;

  int nwg = gridDim.x;
  int swz = (blockIdx.x & 7) * (nwg >> 3) + (blockIdx.x >> 3);
  int bx = swz % nbx, by = swz / nbx;
  int m0 = by * 256, n0 = bx * 256;

  const int rA = w * 8 + (l >> 3);
  const int csw = ((l & 7) ^ (l >> 3)) * 8;  // inverse-swizzled source col
  const __bf16* As_[2][2];
  const __bf16* Bs_[2][2];
#pragma unroll
  for (int h = 0; h < 2; h++)
#pragma unroll
    for (int p = 0; p < 2; p++) {
      As_[h][p] = A + (size_t)(m0 + h * 128 + p * 64 + rA) * K + csw;
      Bs_[h][p] = Bt + (size_t)(n0 + h * 128 + p * 64 + rA) * K + csw;
    }

  auto stageA = [&](int par, int h, int kt) {
#pragma unroll
    for (int p = 0; p < 2; p++)
      gload16(As_[h][p] + kt * 64,
              (const __bf16*)(lds + par * 32768 + h * 16384 + p * 8192 + w * 1024));
  };
  auto stageB = [&](int par, int h, int kt) {
#pragma unroll
    for (int p = 0; p < 2; p++)
      gload16(Bs_[h][p] + kt * 64,
              (const __bf16*)(lds + 65536 + par * 32768 + h * 16384 + p * 8192 + w * 1024));
  };

  const int arbase = (w >> 2) * 64 + lrow;
  const int brbase = (w & 3) * 32 + lrow;

  bf16x8 aA[4][2];
  bf16x8 bB[2][2][2];

  auto readA = [&](int par, int ah) {
#pragma unroll
    for (int i = 0; i < 4; i++)
#pragma unroll
      for (int kk = 0; kk < 2; kk++)
        aA[i][kk] = *reinterpret_cast<const bf16x8*>(
            lds + par * 32768 + (arbase + i * 16 + ah * 128) * 128 +
            ((kk * 64 + lg * 16) ^ sw));
  };
  auto readB = [&](int par, int bh) {
#pragma unroll
    for (int j = 0; j < 2; j++)
#pragma unroll
      for (int kk = 0; kk < 2; kk++)
        bB[bh][j][kk] = *reinterpret_cast<const bf16x8*>(
            lds + 65536 + par * 32768 + (brbase + j * 16 + bh * 128) * 128 +
            ((kk * 64 + lg * 16) ^ sw));
  };

  f32x4 acc[8][4];
#pragma unroll
  for (int i = 0; i < 8; i++)
#pragma unroll
    for (int j = 0; j < 4; j++) {
      acc[i][j][0] = 0.f; acc[i][j][1] = 0.f; acc[i][j][2] = 0.f; acc[i][j][3] = 0.f;
    }

  const int NT = K >> 6;

  stageA(0, 0, 0); stageB(0, 0, 0);
  stageA(0, 1, 0); stageB(0, 1, 0);
  stageA(1, 0, 1); stageB(1, 0, 1);
  VMCNT8();
  SBAR();

#define MFMA_QUAD(AH, BH)                                                   \
  __builtin_amdgcn_s_setprio(1);                                            \
  _Pragma("unroll") for (int i4 = 0; i4 < 4; i4++)                          \
      _Pragma("unroll") for (int j2 = 0; j2 < 2; j2++)                      \
          _Pragma("unroll") for (int kk = 0; kk < 2; kk++)                  \
              acc[(AH)*4 + i4][(BH)*2 + j2] =                               \
                  mfma16(aA[i4][kk], bB[BH][j2][kk], acc[(AH)*4 + i4][(BH)*2 + j2]); \
  __builtin_amdgcn_s_setprio(0);

#define GTILE256(PAR, TT)                                                   \
  {                                                                         \
    const int t1n = ((TT) + 1 < NT) ? (TT) + 1 : 0;                         \
    const int t2n = ((TT) + 2 < NT) ? (TT) + 2 : 0;                         \
    readA(PAR, 0);                                                          \
    readB(PAR, 0);                                                          \
    stageA(PAR ^ 1, 1, t1n);                                                \
    stageB(PAR ^ 1, 1, t1n);                                                \
    VMCNT8();                                                               \
    SBAR();                                                                 \
    MFMA_QUAD(0, 0);                                                        \
    SBAR();                                                                 \
    readB(PAR, 1);                                                          \
    stageA(PAR, 0, t2n);                                                    \
    SBAR();                                                                 \
    MFMA_QUAD(0, 1);                                                        \
    SBAR();                                                                 \
    readA(PAR, 1);                                                          \
    stageB(PAR, 0, t2n);                                                    \
    SBAR();                                                                 \
    MFMA_QUAD(1, 0);                                                        \
    MFMA_QUAD(1, 1);                                                        \
    VMCNT8();                                                               \
    SBAR();                                                                 \
  }

  for (int t = 0; t < NT; t += 2) {
    GTILE256(0, t);
    GTILE256(1, t + 1);
  }
#undef GTILE256
#undef MFMA_QUAD

#pragma unroll
  for (int i = 0; i < 8; i++) {
    int row = m0 + (w >> 2) * 64 + (i & 3) * 16 + (i >> 2) * 128 + lg * 4;
#pragma unroll
    for (int j = 0; j < 4; j++) {
      int col = n0 + (w & 3) * 32 + (j & 1) * 16 + (j >> 1) * 128 + lrow;
#pragma unroll
      for (int jj = 0; jj < 4; jj++)
        C[(size_t)(row + jj) * ldc + col] = (CT)acc[i][j][jj];
    }
  }
}

// ---------------------------------------------------------------------------
// 256x128 GEMM, deep-pipelined (R11 version, unchanged).
// ---------------------------------------------------------------------------
template<typename CT>
__global__ __launch_bounds__(512, 2) void gemm128(const __bf16* __restrict__ A,
                                                  const __bf16* __restrict__ Bt,
                                                  CT* __restrict__ C,
                                                  int K, int ldc, int nbx) {
  __shared__ char lds[98304];
  const int tid = threadIdx.x;
  const int l = tid & 63, w = tid >> 6;
  const int lrow = l & 15, lg = l >> 4;
  const int sw = (lrow & 7) << 4;

  int nwg = gridDim.x;
  int swz = (blockIdx.x & 7) * (nwg >> 3) + (blockIdx.x >> 3);
  int bx = swz % nbx, by = swz / nbx;
  int m0 = by * 256, n0 = bx * 128;

  const int rA = w * 8 + (l >> 3);
  const int csw = ((l & 7) ^ (l >> 3)) * 8;
  const __bf16* As_[2][2];
  const __bf16* Bs_[2];
#pragma unroll
  for (int h = 0; h < 2; h++)
#pragma unroll
    for (int p = 0; p < 2; p++)
      As_[h][p] = A + (size_t)(m0 + h * 128 + p * 64 + rA) * K + csw;
#pragma unroll
  for (int p = 0; p < 2; p++)
    Bs_[p] = Bt + (size_t)(n0 + p * 64 + rA) * K + csw;

  auto stageA = [&](int par, int h, int kt) {
#pragma unroll
    for (int p = 0; p < 2; p++)
      gload16(As_[h][p] + kt * 64,
              (const __bf16*)(lds + par * 32768 + h * 16384 + p * 8192 + w * 1024));
  };
  auto stageB = [&](int par, int kt) {
#pragma unroll
    for (int p = 0; p < 2; p++)
      gload16(Bs_[p] + kt * 64,
              (const __bf16*)(lds + 65536 + par * 16384 + p * 8192 + w * 1024));
  };

  const int arbase = (w >> 2) * 64 + lrow;
  const int brbase = (w & 3) * 32 + lrow;

  bf16x8 aA[4][2];
  bf16x8 bB[2][2];

  auto readA = [&](int par, int ah) {
#pragma unroll
    for (int i = 0; i < 4; i++)
#pragma unroll
      for (int kk = 0; kk < 2; kk++)
        aA[i][kk] = *reinterpret_cast<const bf16x8*>(
            lds + par * 32768 + (arbase + i * 16 + ah * 128) * 128 +
            ((kk * 64 + lg * 16) ^ sw));
  };
  auto readB = [&](int par) {
#pragma unroll
    for (int j = 0; j < 2; j++)
#pragma unroll
      for (int kk = 0; kk < 2; kk++)
        bB[j][kk] = *reinterpret_cast<const bf16x8*>(
            lds + 65536 + par * 16384 + (brbase + j * 16) * 128 +
            ((kk * 64 + lg * 16) ^ sw));
  };

  f32x4 acc[8][2];
#pragma unroll
  for (int i = 0; i < 8; i++)
#pragma unroll
    for (int j = 0; j < 2; j++) {
      acc[i][j][0] = 0.f; acc[i][j][1] = 0.f; acc[i][j][2] = 0.f; acc[i][j][3] = 0.f;
    }

  const int NT = K >> 6;

  stageA(0, 0, 0); stageB(0, 0);
  stageA(0, 1, 0); stageB(1, 1); stageA(1, 0, 1);
  VMCNT6();
  SBAR();

#define MFMA_HALF(AH)                                                        \
  __builtin_amdgcn_s_setprio(1);                                             \
  _Pragma("unroll") for (int i4 = 0; i4 < 4; i4++)                           \
      _Pragma("unroll") for (int j2 = 0; j2 < 2; j2++)                       \
          _Pragma("unroll") for (int kk = 0; kk < 2; kk++)                   \
              acc[(AH)*4 + i4][j2] =                                         \
                  mfma16(aA[i4][kk], bB[j2][kk], acc[(AH)*4 + i4][j2]);      \
  __builtin_amdgcn_s_setprio(0);

#define GTILE128(PAR, TT)                                                    \
  {                                                                          \
    const int t1n = ((TT) + 1 < NT) ? (TT) + 1 : 0;                          \
    const int t2n = ((TT) + 2 < NT) ? (TT) + 2 : 0;                          \
    readA(PAR, 0);                                                           \
    readB(PAR);                                                              \
    stageA(PAR ^ 1, 1, t1n);                                                 \
    VMCNT6();                                                                \
    SBAR();                                                                  \
    MFMA_HALF(0);                                                            \
    SBAR();                                                                  \
    readA(PAR, 1);                                                           \
    stageB(PAR, t2n);                                                        \
    stageA(PAR, 0, t2n);                                                     \
    SBAR();                                                                  \
    MFMA_HALF(1);                                                            \
    VMCNT6();                                                                \
    SBAR();                                                                  \
  }

  for (int t = 0; t < NT; t += 2) {
    GTILE128(0, t);
    GTILE128(1, t + 1);
  }
#undef GTILE128
#undef MFMA_HALF

#pragma unroll
  for (int i = 0; i < 8; i++) {
    int row = m0 + (w >> 2) * 64 + (i & 3) * 16 + (i >> 2) * 128 + lg * 4;
#pragma unroll
    for (int j = 0; j < 2; j++) {
      int col = n0 + (w & 3) * 32 + j * 16 + lrow;
#pragma unroll
      for (int jj = 0; jj < 4; jj++)
        C[(size_t)(row + jj) * ldc + col] = (CT)acc[i][j][jj];
    }
  }
}

// ---------------------------------------------------------------------------
// RoPE, in-place on fused qkv buffer, vectorized.
// ---------------------------------------------------------------------------
__global__ __launch_bounds__(256) void rope_kernel(__bf16* __restrict__ qkv,
                                                   const int* __restrict__ pos) {
  int row = blockIdx.x;
  int t = threadIdx.x;
  float p = (float)pos[row];
  __bf16* rbase = qkv + (size_t)row * QKVW;

  {
    int head = t >> 3, chunk = t & 7;
    __bf16* base = rbase + head * HD + chunk * 8;
    bf16x8 x1 = *reinterpret_cast<const bf16x8*>(base);
    bf16x8 x2 = *reinterpret_cast<const bf16x8*>(base + 64);
    bf16x8 o1, o2;
#pragma unroll
    for (int e = 0; e < 8; e++) {
      float ang = p * exp2f(-0.20762050f * (float)(chunk * 8 + e));
      float s, c;
      __sincosf(ang, &s, &c);
      float a = (float)x1[e], b2 = (float)x2[e];
      o1[e] = (__bf16)(a * c - b2 * s);
      o2[e] = (__bf16)(b2 * c + a * s);
    }
    *reinterpret_cast<bf16x8*>(base) = o1;
    *reinterpret_cast<bf16x8*>(base + 64) = o2;
  }
  if (t < 64) {
    int head = t >> 3, chunk = t & 7;
    __bf16* base = rbase + 4096 + head * HD + chunk * 8;
    bf16x8 x1 = *reinterpret_cast<const bf16x8*>(base);
    bf16x8 x2 = *reinterpret_cast<const bf16x8*>(base + 64);
    bf16x8 o1, o2;
#pragma unroll
    for (int e = 0; e < 8; e++) {
      float ang = p * exp2f(-0.20762050f * (float)(chunk * 8 + e));
      float s, c;
      __sincosf(ang, &s, &c);
      float a = (float)x1[e], b2 = (float)x2[e];
      o1[e] = (__bf16)(a * c - b2 * s);
      o2[e] = (__bf16)(b2 * c + a * s);
    }
    *reinterpret_cast<bf16x8*>(base) = o1;
    *reinterpret_cast<bf16x8*>(base + 64) = o2;
  }
}

// ---------------------------------------------------------------------------
// Flash attention, causal, GQA. 512 blocks (2/CU), heavy-first, 8 waves x
// 32 q-rows, KVBLK=64, K/V^T reg-staged to XOR-swizzled LDS, T14 split.
// SWAPPED QK^T (mfma(K,Q)): S[kv=kv0+c*16+lg*4+jj][q=q0w+mi*16+lrow] —
// each lane holds 16 kv-values of ONE q-row per mi. Row state m/ssum is
// per-lane (replicated across the 4 lg lanes of a row). With pi-permuted V
// (tvt), the PV A-frag is IN-LANE: pa[mi][kvs][j] = P[c=2*kvs+(j&1)][r=j>>1]
// — no P LDS, no P writes/reads, no per-tile shfl. Guarded reduce: slow path
// (rare) does 2 shfl_xor + 8 bpermute redistribution for the ov rescale.
// PV output layout: O[q=lg*4+jj][d=n*16+lrow] (epilogue rinv redistributed
// via 8 bpermutes once).
// ---------------------------------------------------------------------------
__global__ __launch_bounds__(512, 4) void attn_kernel(const __bf16* __restrict__ qkv,
                                                      const __bf16* __restrict__ vt,
                                                      __bf16* __restrict__ out) {
  __shared__ __bf16 Ks[64 * 128];      // [kv][d], swizzled, 16 KB
  __shared__ __bf16 Vs[128 * 64];      // [d][kv'], swizzled, 16 KB

  int tid = threadIdx.x;
  int l = tid & 63, w = tid >> 6;
  int bid = blockIdx.x;
  int qblk = 7 - (bid >> 6);           // heavy blocks first
  int rem = bid & 63;
  int h = rem & 31, b = rem >> 5;
  int kvh = h >> 2;
  int q0w = qblk * 256 + w * 32;
  int lrow = l & 15, lg = l >> 4;
  int sw = (lrow & 7) << 4;
  const float SCL = 0.08838834764831845f * 1.4426950408889634f;  // 1/sqrt(128)*log2e

  const __bf16* kbase = qkv + (size_t)(b * S_LEN) * QKVW + 4096 + kvh * HD;
  const __bf16* vbase = vt + ((size_t)(b * NKV + kvh) * HD) * S_LEN;

  int krow = tid >> 3;
  int kslot = (tid & 7) * 2;
  int vrow = tid >> 2;
  int vslot = (tid & 3) * 2;
  char* KsB = (char*)Ks;
  char* VsB = (char*)Vs;
  int koff0 = krow * 256 + ((kslot * 16) ^ ((krow & 7) << 4));
  int koff1 = krow * 256 + (((kslot + 1) * 16) ^ ((krow & 7) << 4));
  int voff0 = vrow * 128 + ((vslot * 16) ^ ((vrow & 7) << 4));
  int voff1 = vrow * 128 + (((vslot + 1) * 16) ^ ((vrow & 7) << 4));
  const __bf16* kg = kbase + (size_t)krow * QKVW + kslot * 8;
  const __bf16* vg = vbase + (size_t)vrow * S_LEN + vslot * 8;

  // Q fragments, pre-scaled (per-lane data doubles as the MFMA B-operand)
  bf16x8 qf[2][4];
#pragma unroll
  for (int mi = 0; mi < 2; mi++) {
    const __bf16* qp = qkv + (size_t)(b * S_LEN + q0w + mi * 16 + lrow) * QKVW + h * HD + lg * 8;
#pragma unroll
    for (int kk = 0; kk < 4; kk++) {
      bf16x8 t = *reinterpret_cast<const bf16x8*>(qp + kk * 32);
#pragma unroll
      for (int e = 0; e < 8; e++) t[e] = (__bf16)((float)t[e] * SCL);
      qf[mi][kk] = t;
    }
  }

  f32x4 ov[2][8];
#pragma unroll
  for (int mi = 0; mi < 2; mi++)
#pragma unroll
    for (int n = 0; n < 8; n++) {
      ov[mi][n][0] = 0.f; ov[mi][n][1] = 0.f; ov[mi][n][2] = 0.f; ov[mi][n][3] = 0.f;
    }
  float m[2], ssum[2];
  m[0] = -3.0e38f; m[1] = -3.0e38f;
  ssum[0] = 0.f; ssum[1] = 0.f;

  int nt = 4 * qblk + 4;
  bf16x8 kr0, kr1, vr0, vr1;

  kr0 = *reinterpret_cast<const bf16x8*>(kg);
  kr1 = *reinterpret_cast<const bf16x8*>(kg + 8);
  vr0 = *reinterpret_cast<const bf16x8*>(vg);
  vr1 = *reinterpret_cast<const bf16x8*>(vg + 8);
  *reinterpret_cast<bf16x8*>(KsB + koff0) = kr0;
  *reinterpret_cast<bf16x8*>(KsB + koff1) = kr1;
  *reinterpret_cast<bf16x8*>(VsB + voff0) = vr0;
  *reinterpret_cast<bf16x8*>(VsB + voff1) = vr1;
  __syncthreads();

  for (int t = 0;; t++) {
    int kv0 = t * 64;
    bool more = (t + 1 < nt);
    if (more) {
      int kvn = kv0 + 64;
      kr0 = *reinterpret_cast<const bf16x8*>(kg + (size_t)kvn * QKVW);
      kr1 = *reinterpret_cast<const bf16x8*>(kg + (size_t)kvn * QKVW + 8);
      vr0 = *reinterpret_cast<const bf16x8*>(vg + kvn);
      vr1 = *reinterpret_cast<const bf16x8*>(vg + kvn + 8);
    }

    bool active = (kv0 <= q0w + 31);
    if (active) {
      // ---- swapped QK^T: sc[mi][c] = S^T tile (rows=kv, cols=q)
      f32x4 sc[2][4];
#pragma unroll
      for (int mi = 0; mi < 2; mi++)
#pragma unroll
        for (int c = 0; c < 4; c++) {
          sc[mi][c][0] = 0.f; sc[mi][c][1] = 0.f; sc[mi][c][2] = 0.f; sc[mi][c][3] = 0.f;
        }
#pragma unroll
      for (int c = 0; c < 4; c++) {
        int rb = (c * 16 + lrow) * 256;
#pragma unroll
        for (int kk = 0; kk < 4; kk++) {
          bf16x8 kf = *reinterpret_cast<const bf16x8*>(KsB + rb + ((kk * 64 + lg * 16) ^ sw));
          sc[0][c] = mfma16(kf, qf[0][kk], sc[0][c]);
          sc[1][c] = mfma16(kf, qf[1][kk], sc[1][c]);
        }
      }

      // ---- causal mask: kv = kv0 + c*16 + lg*4 + jj ; q = q0w + mi*16 + lrow
      bool bound = (kv0 + 64 > q0w);
      if (bound) {
#pragma unroll
        for (int mi = 0; mi < 2; mi++) {
          int qidx = q0w + mi * 16 + lrow;
#pragma unroll
          for (int jj = 0; jj < 4; jj++) {
            int kvb = kv0 + lg * 4 + jj;
            if (kvb > qidx)      sc[mi][0][jj] = -3.0e38f;
            if (kvb + 16 > qidx) sc[mi][1][jj] = -3.0e38f;
            if (kvb + 32 > qidx) sc[mi][2][jj] = -3.0e38f;
            if (kvb + 48 > qidx) sc[mi][3][jj] = -3.0e38f;
          }
        }
      }

      // ---- per-lane growth check (all 16 values in-lane belong to q=lrow)
      float lm[2];
      bool lanegrow = false;
#pragma unroll
      for (int mi = 0; mi < 2; mi++) {
        float a0 = fmaxf(fmaxf(sc[mi][0][0], sc[mi][0][1]), fmaxf(sc[mi][0][2], sc[mi][0][3]));
        float a1 = fmaxf(fmaxf(sc[mi][1][0], sc[mi][1][1]), fmaxf(sc[mi][1][2], sc[mi][1][3]));
        float a2 = fmaxf(fmaxf(sc[mi][2][0], sc[mi][2][1]), fmaxf(sc[mi][2][2], sc[mi][2][3]));
        float a3 = fmaxf(fmaxf(sc[mi][3][0], sc[mi][3][1]), fmaxf(sc[mi][3][2], sc[mi][3][3]));
        lm[mi] = fmaxf(fmaxf(a0, a1), fmaxf(a2, a3));
        lanegrow |= (lm[mi] > m[mi] + 8.0f);
      }

      if (__any(lanegrow)) {
        // rare slow path: reduce row max over the 4 lg lanes, rescale
        float es[2];
#pragma unroll
        for (int mi = 0; mi < 2; mi++) {
          float r = lm[mi];
          r = fmaxf(r, __shfl_xor(r, 16));
          r = fmaxf(r, __shfl_xor(r, 32));
          float mo = m[mi];
          bool grow = (r > mo + 8.0f);
          float mn = grow ? r : mo;
          float e = grow ? exp2f(mo - r) : 1.0f;
          es[mi] = e;
          m[mi] = mn;
          ssum[mi] *= e;
        }
        // redistribute: ov rows are q=lg*4+jj, es lives at q=lrow lanes
        float esv[2][4];
#pragma unroll
        for (int mi = 0; mi < 2; mi++)
#pragma unroll
          for (int jj = 0; jj < 4; jj++)
            esv[mi][jj] = __shfl(es[mi], lg * 4 + jj);
#pragma unroll
        for (int mi = 0; mi < 2; mi++)
#pragma unroll
          for (int n = 0; n < 8; n++)
#pragma unroll
            for (int jj = 0; jj < 4; jj++) ov[mi][n][jj] *= esv[mi][jj];
      }

      // ---- exp2 + in-register P pack (pi order): pa[mi][c>>1][(r<<1)|(c&1)]
      bf16x8 pa[2][2];
#pragma unroll
      for (int mi = 0; mi < 2; mi++) {
        float mn = m[mi];
#pragma unroll
        for (int c = 0; c < 4; c++)
#pragma unroll
          for (int r = 0; r < 4; r++) {
            float p = exp2f(sc[mi][c][r] - mn);
            ssum[mi] += p;
            pa[mi][c >> 1][(r << 1) | (c & 1)] = (__bf16)p;
          }
      }

      // ---- PV: A = pa (in-register), B = pi-permuted V^T from LDS
#pragma unroll
      for (int kvs = 0; kvs < 2; kvs++) {
#pragma unroll
        for (int n = 0; n < 8; n++) {
          bf16x8 vf = *reinterpret_cast<const bf16x8*>(
              VsB + (n * 16 + lrow) * 128 + ((kvs * 64 + lg * 16) ^ sw));
          ov[0][n] = mfma16(pa[0][kvs], vf, ov[0][n]);
          ov[1][n] = mfma16(pa[1][kvs], vf, ov[1][n]);
        }
      }
    }

    if (!more) break;
    __syncthreads();
    *reinterpret_cast<bf16x8*>(KsB + koff0) = kr0;
    *reinterpret_cast<bf16x8*>(KsB + koff1) = kr1;
    *reinterpret_cast<bf16x8*>(VsB + voff0) = vr0;
    *reinterpret_cast<bf16x8*>(VsB + voff1) = vr1;
    __syncthreads();
  }

  // ---- epilogue: reduce ssum over lg, redistribute to ov's q-mapping, store
  float rs[2];
#pragma unroll
  for (int mi = 0; mi < 2; mi++) {
    float s = ssum[mi];
    s += __shfl_xor(s, 16);
    s += __shfl_xor(s, 32);
    rs[mi] = s;
  }
  float rinv[2][4];
#pragma unroll
  for (int mi = 0; mi < 2; mi++)
#pragma unroll
    for (int jj = 0; jj < 4; jj++)
      rinv[mi][jj] = 1.0f / __shfl(rs[mi], lg * 4 + jj);
#pragma unroll
  for (int mi = 0; mi < 2; mi++)
#pragma unroll
    for (int n = 0; n < 8; n++)
#pragma unroll
      for (int jj = 0; jj < 4; jj++) {
        out[(size_t)(b * S_LEN + q0w + mi * 16 + lg * 4 + jj) * HIDDEN + h * HD + n * 16 + lrow] =
            (__bf16)(ov[mi][n][jj] * rinv[mi][jj]);
      }
}

// ---------------------------------------------------------------------------
// Workspace layout (bytes), total 142606336:
//   h_bf / a_buf (aliased) @ 0          33554432   bf16 [4096][4096]
//   Wt (qkv^T, later Wo^T) @ 33554432   50331648   bf16 [6144][4096]
//   qkv_buf                @ 83886080   50331648   bf16 [4096][6144]
//   vt_buf                 @ 134217728   8388608   bf16 [16][128][2048]
// ---------------------------------------------------------------------------
extern "C" void kernel_launch(void* const* d_in, const int* in_sizes, int n_in,
                              void* d_out, int out_size, void* d_ws, size_t ws_size,
                              hipStream_t stream) {
  const float* hidden = (const float*)d_in[0];
  const int* posids   = (const int*)d_in[1];
  const float* Wq     = (const float*)d_in[2];
  const float* Wk     = (const float*)d_in[3];
  const float* Wv     = (const float*)d_in[4];
  const float* Wo     = (const float*)d_in[5];
  float* out = (float*)d_out;

  char* ws = (char*)d_ws;
  __bf16* h_bf    = (__bf16*)(ws + 0);
  __bf16* a_buf   = h_bf;  // aliased: h last read by QKV GEMMs, before attn writes
  __bf16* Wt      = (__bf16*)(ws + 33554432);
  __bf16* qkv_buf = (__bf16*)(ws + 83886080);
  __bf16* vt_buf  = (__bf16*)(ws + 134217728);

  dim3 b256(256), b328(32, 8), b512(512);

  // 1. hidden -> bf16
  cvt_kernel<<<dim3(MROWS * HIDDEN / (256 * 8)), b256, 0, stream>>>(hidden, h_bf, MROWS * HIDDEN);

  // 2. fused weight transpose: Wt = [Wq^T ; Wk^T ; Wv^T]  [6144][4096]
  tcvt3_kernel<<<dim3(128, 128, 3), b328, 0, stream>>>(Wq, Wk, Wv, Wt);

  // 3a. QKV main: cols [0,4096) via 256^2 tiles -> 256 blocks (1 round)
  gemm256<__bf16><<<dim3(256), b512, 0, stream>>>(
      h_bf, Wt, qkv_buf, HIDDEN, QKVW, 4096 / 256);
  // 3b. QKV tail: cols [4096,6144) via 256x128 tiles -> 256 blocks
  gemm128<__bf16><<<dim3(256), b512, 0, stream>>>(
      h_bf, Wt + (size_t)4096 * 4096, qkv_buf + 4096, HIDDEN, QKVW, 2048 / 128);

  // 4. RoPE on q,k (in fused buffer), vectorized
  rope_kernel<<<dim3(MROWS), b256, 0, stream>>>(qkv_buf, posids);

  // 5. V^T (pi-permuted kv within each 64-tile)
  tvt_kernel<<<dim3(HD / 32, S_LEN / 32, BATCH * NKV), b328, 0, stream>>>(qkv_buf, vt_buf);

  // 6. attention -> a_buf  (512 blocks, heavy-first, 2 blocks/CU)
  attn_kernel<<<dim3(8 * NH * BATCH), b512, 0, stream>>>(qkv_buf, vt_buf, a_buf);

  // 7. Wo^T (reuse Wt)
  tcvt_f32<<<dim3(HIDDEN / 32, HIDDEN / 32), b328, 0, stream>>>(Wo, Wt, HIDDEN, HIDDEN);

  // 8. out = a @ Wo  (fp32 out; 256 blocks = 1 balanced round)
  gemm256<float><<<dim3(256), b512, 0, stream>>>(
      a_buf, Wt, out, HIDDEN, HIDDEN, HIDDEN / 256);
}

// Round 13
// 460.379 us; speedup vs baseline: 1.8414x; 1.8414x over previous
//
#include <hip/hip_runtime.h>
#include <hip/hip_bf16.h>
#include <math.h>

#define HIDDEN 4096
#define NH 32
#define NKV 8
#define HD 128
#define S_LEN 2048
#define BATCH 2
#define MROWS (BATCH * S_LEN)  // 4096
#define QKVW 6144              // fused q|k|v row width

typedef __attribute__((ext_vector_type(8))) __bf16 bf16x8;
typedef __attribute__((ext_vector_type(4))) float f32x4;

__device__ __forceinline__ f32x4 mfma16(bf16x8 a, bf16x8 b, f32x4 c) {
  return __builtin_amdgcn_mfma_f32_16x16x32_bf16(a, b, c, 0, 0, 0);
}

// async global->LDS, 16B/lane; LDS dest = wave-uniform base, HW adds lane*16.
__device__ __forceinline__ void gload16(const __bf16* g, const __bf16* l) {
  __builtin_amdgcn_global_load_lds(
      (const __attribute__((address_space(1))) void*)g,
      (__attribute__((address_space(3))) void*)l, 16, 0, 0);
}

#define SBAR()                          \
  do {                                  \
    __builtin_amdgcn_sched_barrier(0);  \
    __builtin_amdgcn_s_barrier();       \
    __builtin_amdgcn_sched_barrier(0);  \
  } while (0)

#define VMCNT8()                                              \
  do {                                                        \
    __builtin_amdgcn_sched_barrier(0);                        \
    asm volatile("s_waitcnt vmcnt(8)" ::: "memory");          \
  } while (0)

#define VMCNT6()                                              \
  do {                                                        \
    __builtin_amdgcn_sched_barrier(0);                        \
    asm volatile("s_waitcnt vmcnt(6)" ::: "memory");          \
  } while (0)

// ---------------------------------------------------------------------------
// fp32 -> bf16 elementwise convert (vectorized)
// ---------------------------------------------------------------------------
__global__ __launch_bounds__(256) void cvt_kernel(const float* __restrict__ in,
                                                  __bf16* __restrict__ out, int n) {
  int i = (blockIdx.x * 256 + threadIdx.x) * 8;
  if (i >= n) return;
  float4 a = *reinterpret_cast<const float4*>(in + i);
  float4 b = *reinterpret_cast<const float4*>(in + i + 4);
  bf16x8 t;
  t[0] = (__bf16)a.x; t[1] = (__bf16)a.y; t[2] = (__bf16)a.z; t[3] = (__bf16)a.w;
  t[4] = (__bf16)b.x; t[5] = (__bf16)b.y; t[6] = (__bf16)b.z; t[7] = (__bf16)b.w;
  *reinterpret_cast<bf16x8*>(out + i) = t;
}

// ---------------------------------------------------------------------------
// Fused weight transpose+convert: z=0 Wq (4096 cols), z=1 Wk, z=2 Wv (1024).
// ---------------------------------------------------------------------------
__global__ __launch_bounds__(256) void tcvt3_kernel(const float* __restrict__ Wq,
                                                    const float* __restrict__ Wk,
                                                    const float* __restrict__ Wv,
                                                    __bf16* __restrict__ Wt) {
  __shared__ float t[32][33];
  int z = blockIdx.z;
  const float* in;
  __bf16* out;
  int C;
  if (z == 0)      { in = Wq; out = Wt;                         C = 4096; }
  else if (z == 1) { in = Wk; out = Wt + (size_t)4096 * 4096;   C = 1024; }
  else             { in = Wv; out = Wt + (size_t)5120 * 4096;   C = 1024; }
  if ((int)blockIdx.x * 32 >= C) return;
  int tx = threadIdx.x, ty = threadIdx.y;
  int r0 = blockIdx.y * 32, c0 = blockIdx.x * 32;
#pragma unroll
  for (int i = 0; i < 4; i++)
    t[ty + i * 8][tx] = in[(size_t)(r0 + ty + i * 8) * C + c0 + tx];
  __syncthreads();
#pragma unroll
  for (int i = 0; i < 4; i++)
    out[(size_t)(c0 + ty + i * 8) * 4096 + r0 + tx] = (__bf16)t[tx][ty + i * 8];
}

// single transpose for Wo
__global__ __launch_bounds__(256) void tcvt_f32(const float* __restrict__ in,
                                                __bf16* __restrict__ out,
                                                int R, int C) {
  __shared__ float t[32][33];
  int tx = threadIdx.x, ty = threadIdx.y;
  int r0 = blockIdx.y * 32, c0 = blockIdx.x * 32;
#pragma unroll
  for (int i = 0; i < 4; i++)
    t[ty + i * 8][tx] = in[(size_t)(r0 + ty + i * 8) * C + c0 + tx];
  __syncthreads();
#pragma unroll
  for (int i = 0; i < 4; i++)
    out[(size_t)(c0 + ty + i * 8) * R + r0 + tx] = (__bf16)t[tx][ty + i * 8];
}

// ---------------------------------------------------------------------------
// V transpose: qkv -> vt [B*NKV][HD][S], with pair-interleave permutation
// pi(16a+r) = 32*(a>>1) + 2r + (a&1) applied WITHIN each 64-kv tile.
// Writes stay in the same 64B segment -> coalescing unchanged. attn's
// in-register P packing uses the same pi so PV contracts consistently.
// ---------------------------------------------------------------------------
__global__ __launch_bounds__(256) void tvt_kernel(const __bf16* __restrict__ qkv,
                                                  __bf16* __restrict__ vt) {
  __shared__ __bf16 t[32][33];
  int tx = threadIdx.x, ty = threadIdx.y;
  int z = blockIdx.z;
  int b = z >> 3, kvh = z & 7;
  int kv0 = blockIdx.y * 32, d0 = blockIdx.x * 32;
#pragma unroll
  for (int i = 0; i < 4; i++)
    t[ty + i * 8][tx] =
        qkv[(size_t)(b * S_LEN + kv0 + ty + i * 8) * QKVW + 5120 + kvh * HD + d0 + tx];
  __syncthreads();
  int cperm = kv0 + 2 * (tx & 15) + (tx >> 4);
#pragma unroll
  for (int i = 0; i < 4; i++)
    vt[((size_t)z * HD + d0 + ty + i * 8) * S_LEN + cperm] = t[tx][ty + i * 8];
}

// ---------------------------------------------------------------------------
// 256x256 GEMM, deep-pipelined (R11 version, unchanged).
// ---------------------------------------------------------------------------
template<typename CT>
__global__ __launch_bounds__(512, 2) void gemm256(const __bf16* __restrict__ A,
                                                  const __bf16* __restrict__ Bt,
                                                  CT* __restrict__ C,
                                                  int K, int ldc, int nbx) {
  __shared__ char lds[131072];
  const int tid = threadIdx.x;
  const int l = tid & 63, w = tid >> 6;
  const int lrow = l & 15, lg = l >> 4;
  const int sw = (lrow & 7) << 4;

  int nwg = gridDim.x;
  int swz = (blockIdx.x & 7) * (nwg >> 3) + (blockIdx.x >> 3);
  int bx = swz % nbx, by = swz / nbx;
  int m0 = by * 256, n0 = bx * 256;

  const int rA = w * 8 + (l >> 3);
  const int csw = ((l & 7) ^ (l >> 3)) * 8;  // inverse-swizzled source col
  const __bf16* As_[2][2];
  const __bf16* Bs_[2][2];
#pragma unroll
  for (int h = 0; h < 2; h++)
#pragma unroll
    for (int p = 0; p < 2; p++) {
      As_[h][p] = A + (size_t)(m0 + h * 128 + p * 64 + rA) * K + csw;
      Bs_[h][p] = Bt + (size_t)(n0 + h * 128 + p * 64 + rA) * K + csw;
    }

  auto stageA = [&](int par, int h, int kt) {
#pragma unroll
    for (int p = 0; p < 2; p++)
      gload16(As_[h][p] + kt * 64,
              (const __bf16*)(lds + par * 32768 + h * 16384 + p * 8192 + w * 1024));
  };
  auto stageB = [&](int par, int h, int kt) {
#pragma unroll
    for (int p = 0; p < 2; p++)
      gload16(Bs_[h][p] + kt * 64,
              (const __bf16*)(lds + 65536 + par * 32768 + h * 16384 + p * 8192 + w * 1024));
  };

  const int arbase = (w >> 2) * 64 + lrow;
  const int brbase = (w & 3) * 32 + lrow;

  bf16x8 aA[4][2];
  bf16x8 bB[2][2][2];

  auto readA = [&](int par, int ah) {
#pragma unroll
    for (int i = 0; i < 4; i++)
#pragma unroll
      for (int kk = 0; kk < 2; kk++)
        aA[i][kk] = *reinterpret_cast<const bf16x8*>(
            lds + par * 32768 + (arbase + i * 16 + ah * 128) * 128 +
            ((kk * 64 + lg * 16) ^ sw));
  };
  auto readB = [&](int par, int bh) {
#pragma unroll
    for (int j = 0; j < 2; j++)
#pragma unroll
      for (int kk = 0; kk < 2; kk++)
        bB[bh][j][kk] = *reinterpret_cast<const bf16x8*>(
            lds + 65536 + par * 32768 + (brbase + j * 16 + bh * 128) * 128 +
            ((kk * 64 + lg * 16) ^ sw));
  };

  f32x4 acc[8][4];
#pragma unroll
  for (int i = 0; i < 8; i++)
#pragma unroll
    for (int j = 0; j < 4; j++) {
      acc[i][j][0] = 0.f; acc[i][j][1] = 0.f; acc[i][j][2] = 0.f; acc[i][j][3] = 0.f;
    }

  const int NT = K >> 6;

  stageA(0, 0, 0); stageB(0, 0, 0);
  stageA(0, 1, 0); stageB(0, 1, 0);
  stageA(1, 0, 1); stageB(1, 0, 1);
  VMCNT8();
  SBAR();

#define MFMA_QUAD(AH, BH)                                                   \
  __builtin_amdgcn_s_setprio(1);                                            \
  _Pragma("unroll") for (int i4 = 0; i4 < 4; i4++)                          \
      _Pragma("unroll") for (int j2 = 0; j2 < 2; j2++)                      \
          _Pragma("unroll") for (int kk = 0; kk < 2; kk++)                  \
              acc[(AH)*4 + i4][(BH)*2 + j2] =                               \
                  mfma16(aA[i4][kk], bB[BH][j2][kk], acc[(AH)*4 + i4][(BH)*2 + j2]); \
  __builtin_amdgcn_s_setprio(0);

#define GTILE256(PAR, TT)                                                   \
  {                                                                         \
    const int t1n = ((TT) + 1 < NT) ? (TT) + 1 : 0;                         \
    const int t2n = ((TT) + 2 < NT) ? (TT) + 2 : 0;                         \
    readA(PAR, 0);                                                          \
    readB(PAR, 0);                                                          \
    stageA(PAR ^ 1, 1, t1n);                                                \
    stageB(PAR ^ 1, 1, t1n);                                                \
    VMCNT8();                                                               \
    SBAR();                                                                 \
    MFMA_QUAD(0, 0);                                                        \
    SBAR();                                                                 \
    readB(PAR, 1);                                                          \
    stageA(PAR, 0, t2n);                                                    \
    SBAR();                                                                 \
    MFMA_QUAD(0, 1);                                                        \
    SBAR();                                                                 \
    readA(PAR, 1);                                                          \
    stageB(PAR, 0, t2n);                                                    \
    SBAR();                                                                 \
    MFMA_QUAD(1, 0);                                                        \
    MFMA_QUAD(1, 1);                                                        \
    VMCNT8();                                                               \
    SBAR();                                                                 \
  }

  for (int t = 0; t < NT; t += 2) {
    GTILE256(0, t);
    GTILE256(1, t + 1);
  }
#undef GTILE256
#undef MFMA_QUAD

#pragma unroll
  for (int i = 0; i < 8; i++) {
    int row = m0 + (w >> 2) * 64 + (i & 3) * 16 + (i >> 2) * 128 + lg * 4;
#pragma unroll
    for (int j = 0; j < 4; j++) {
      int col = n0 + (w & 3) * 32 + (j & 1) * 16 + (j >> 1) * 128 + lrow;
#pragma unroll
      for (int jj = 0; jj < 4; jj++)
        C[(size_t)(row + jj) * ldc + col] = (CT)acc[i][j][jj];
    }
  }
}

// ---------------------------------------------------------------------------
// 256x128 GEMM, deep-pipelined (R11 version, unchanged).
// ---------------------------------------------------------------------------
template<typename CT>
__global__ __launch_bounds__(512, 2) void gemm128(const __bf16* __restrict__ A,
                                                  const __bf16* __restrict__ Bt,
                                                  CT* __restrict__ C,
                                                  int K, int ldc, int nbx) {
  __shared__ char lds[98304];
  const int tid = threadIdx.x;
  const int l = tid & 63, w = tid >> 6;
  const int lrow = l & 15, lg = l >> 4;
  const int sw = (lrow & 7) << 4;

  int nwg = gridDim.x;
  int swz = (blockIdx.x & 7) * (nwg >> 3) + (blockIdx.x >> 3);
  int bx = swz % nbx, by = swz / nbx;
  int m0 = by * 256, n0 = bx * 128;

  const int rA = w * 8 + (l >> 3);
  const int csw = ((l & 7) ^ (l >> 3)) * 8;
  const __bf16* As_[2][2];
  const __bf16* Bs_[2];
#pragma unroll
  for (int h = 0; h < 2; h++)
#pragma unroll
    for (int p = 0; p < 2; p++)
      As_[h][p] = A + (size_t)(m0 + h * 128 + p * 64 + rA) * K + csw;
#pragma unroll
  for (int p = 0; p < 2; p++)
    Bs_[p] = Bt + (size_t)(n0 + p * 64 + rA) * K + csw;

  auto stageA = [&](int par, int h, int kt) {
#pragma unroll
    for (int p = 0; p < 2; p++)
      gload16(As_[h][p] + kt * 64,
              (const __bf16*)(lds + par * 32768 + h * 16384 + p * 8192 + w * 1024));
  };
  auto stageB = [&](int par, int kt) {
#pragma unroll
    for (int p = 0; p < 2; p++)
      gload16(Bs_[p] + kt * 64,
              (const __bf16*)(lds + 65536 + par * 16384 + p * 8192 + w * 1024));
  };

  const int arbase = (w >> 2) * 64 + lrow;
  const int brbase = (w & 3) * 32 + lrow;

  bf16x8 aA[4][2];
  bf16x8 bB[2][2];

  auto readA = [&](int par, int ah) {
#pragma unroll
    for (int i = 0; i < 4; i++)
#pragma unroll
      for (int kk = 0; kk < 2; kk++)
        aA[i][kk] = *reinterpret_cast<const bf16x8*>(
            lds + par * 32768 + (arbase + i * 16 + ah * 128) * 128 +
            ((kk * 64 + lg * 16) ^ sw));
  };
  auto readB = [&](int par) {
#pragma unroll
    for (int j = 0; j < 2; j++)
#pragma unroll
      for (int kk = 0; kk < 2; kk++)
        bB[j][kk] = *reinterpret_cast<const bf16x8*>(
            lds + 65536 + par * 16384 + (brbase + j * 16) * 128 +
            ((kk * 64 + lg * 16) ^ sw));
  };

  f32x4 acc[8][2];
#pragma unroll
  for (int i = 0; i < 8; i++)
#pragma unroll
    for (int j = 0; j < 2; j++) {
      acc[i][j][0] = 0.f; acc[i][j][1] = 0.f; acc[i][j][2] = 0.f; acc[i][j][3] = 0.f;
    }

  const int NT = K >> 6;

  stageA(0, 0, 0); stageB(0, 0);
  stageA(0, 1, 0); stageB(1, 1); stageA(1, 0, 1);
  VMCNT6();
  SBAR();

#define MFMA_HALF(AH)                                                        \
  __builtin_amdgcn_s_setprio(1);                                             \
  _Pragma("unroll") for (int i4 = 0; i4 < 4; i4++)                           \
      _Pragma("unroll") for (int j2 = 0; j2 < 2; j2++)                       \
          _Pragma("unroll") for (int kk = 0; kk < 2; kk++)                   \
              acc[(AH)*4 + i4][j2] =                                         \
                  mfma16(aA[i4][kk], bB[j2][kk], acc[(AH)*4 + i4][j2]);      \
  __builtin_amdgcn_s_setprio(0);

#define GTILE128(PAR, TT)                                                    \
  {                                                                          \
    const int t1n = ((TT) + 1 < NT) ? (TT) + 1 : 0;                          \
    const int t2n = ((TT) + 2 < NT) ? (TT) + 2 : 0;                          \
    readA(PAR, 0);                                                           \
    readB(PAR);                                                              \
    stageA(PAR ^ 1, 1, t1n);                                                 \
    VMCNT6();                                                                \
    SBAR();                                                                  \
    MFMA_HALF(0);                                                            \
    SBAR();                                                                  \
    readA(PAR, 1);                                                           \
    stageB(PAR, t2n);                                                        \
    stageA(PAR, 0, t2n);                                                     \
    SBAR();                                                                  \
    MFMA_HALF(1);                                                            \
    VMCNT6();                                                                \
    SBAR();                                                                  \
  }

  for (int t = 0; t < NT; t += 2) {
    GTILE128(0, t);
    GTILE128(1, t + 1);
  }
#undef GTILE128
#undef MFMA_HALF

#pragma unroll
  for (int i = 0; i < 8; i++) {
    int row = m0 + (w >> 2) * 64 + (i & 3) * 16 + (i >> 2) * 128 + lg * 4;
#pragma unroll
    for (int j = 0; j < 2; j++) {
      int col = n0 + (w & 3) * 32 + j * 16 + lrow;
#pragma unroll
      for (int jj = 0; jj < 4; jj++)
        C[(size_t)(row + jj) * ldc + col] = (CT)acc[i][j][jj];
    }
  }
}

// ---------------------------------------------------------------------------
// RoPE, in-place on fused qkv buffer, vectorized.
// ---------------------------------------------------------------------------
__global__ __launch_bounds__(256) void rope_kernel(__bf16* __restrict__ qkv,
                                                   const int* __restrict__ pos) {
  int row = blockIdx.x;
  int t = threadIdx.x;
  float p = (float)pos[row];
  __bf16* rbase = qkv + (size_t)row * QKVW;

  {
    int head = t >> 3, chunk = t & 7;
    __bf16* base = rbase + head * HD + chunk * 8;
    bf16x8 x1 = *reinterpret_cast<const bf16x8*>(base);
    bf16x8 x2 = *reinterpret_cast<const bf16x8*>(base + 64);
    bf16x8 o1, o2;
#pragma unroll
    for (int e = 0; e < 8; e++) {
      float ang = p * exp2f(-0.20762050f * (float)(chunk * 8 + e));
      float s, c;
      __sincosf(ang, &s, &c);
      float a = (float)x1[e], b2 = (float)x2[e];
      o1[e] = (__bf16)(a * c - b2 * s);
      o2[e] = (__bf16)(b2 * c + a * s);
    }
    *reinterpret_cast<bf16x8*>(base) = o1;
    *reinterpret_cast<bf16x8*>(base + 64) = o2;
  }
  if (t < 64) {
    int head = t >> 3, chunk = t & 7;
    __bf16* base = rbase + 4096 + head * HD + chunk * 8;
    bf16x8 x1 = *reinterpret_cast<const bf16x8*>(base);
    bf16x8 x2 = *reinterpret_cast<const bf16x8*>(base + 64);
    bf16x8 o1, o2;
#pragma unroll
    for (int e = 0; e < 8; e++) {
      float ang = p * exp2f(-0.20762050f * (float)(chunk * 8 + e));
      float s, c;
      __sincosf(ang, &s, &c);
      float a = (float)x1[e], b2 = (float)x2[e];
      o1[e] = (__bf16)(a * c - b2 * s);
      o2[e] = (__bf16)(b2 * c + a * s);
    }
    *reinterpret_cast<bf16x8*>(base) = o1;
    *reinterpret_cast<bf16x8*>(base + 64) = o2;
  }
}

// ---------------------------------------------------------------------------
// Flash attention, causal, GQA. 512 blocks, heavy-first, 8 waves x 32 q-rows,
// KVBLK=64, K/V^T reg-staged to XOR-swizzled LDS, T14 split. SWAPPED QK^T
// (mfma(K,Q)): S[kv][q] — lane holds 16 kv of one q-row per mi; in-register
// pi-packed P feeds PV directly (no P LDS, no per-tile shfl). Guarded reduce.
// NOTE: plain __launch_bounds__(512) — R12's (512,4) capped total regs at 128
// (64 arch + 64 acc) and spilled ~1.8 GB/dispatch to scratch. Let the
// allocator take what it needs; no spills is worth more than occupancy here.
// ---------------------------------------------------------------------------
__global__ __launch_bounds__(512) void attn_kernel(const __bf16* __restrict__ qkv,
                                                   const __bf16* __restrict__ vt,
                                                   __bf16* __restrict__ out) {
  __shared__ __bf16 Ks[64 * 128];      // [kv][d], swizzled, 16 KB
  __shared__ __bf16 Vs[128 * 64];      // [d][kv'], swizzled, 16 KB

  int tid = threadIdx.x;
  int l = tid & 63, w = tid >> 6;
  int bid = blockIdx.x;
  int qblk = 7 - (bid >> 6);           // heavy blocks first
  int rem = bid & 63;
  int h = rem & 31, b = rem >> 5;
  int kvh = h >> 2;
  int q0w = qblk * 256 + w * 32;
  int lrow = l & 15, lg = l >> 4;
  int sw = (lrow & 7) << 4;
  const float SCL = 0.08838834764831845f * 1.4426950408889634f;  // 1/sqrt(128)*log2e

  const __bf16* kbase = qkv + (size_t)(b * S_LEN) * QKVW + 4096 + kvh * HD;
  const __bf16* vbase = vt + ((size_t)(b * NKV + kvh) * HD) * S_LEN;

  int krow = tid >> 3;
  int kslot = (tid & 7) * 2;
  int vrow = tid >> 2;
  int vslot = (tid & 3) * 2;
  char* KsB = (char*)Ks;
  char* VsB = (char*)Vs;
  int koff0 = krow * 256 + ((kslot * 16) ^ ((krow & 7) << 4));
  int koff1 = krow * 256 + (((kslot + 1) * 16) ^ ((krow & 7) << 4));
  int voff0 = vrow * 128 + ((vslot * 16) ^ ((vrow & 7) << 4));
  int voff1 = vrow * 128 + (((vslot + 1) * 16) ^ ((vrow & 7) << 4));
  const __bf16* kg = kbase + (size_t)krow * QKVW + kslot * 8;
  const __bf16* vg = vbase + (size_t)vrow * S_LEN + vslot * 8;

  // Q fragments, pre-scaled (per-lane data doubles as the MFMA B-operand)
  bf16x8 qf[2][4];
#pragma unroll
  for (int mi = 0; mi < 2; mi++) {
    const __bf16* qp = qkv + (size_t)(b * S_LEN + q0w + mi * 16 + lrow) * QKVW + h * HD + lg * 8;
#pragma unroll
    for (int kk = 0; kk < 4; kk++) {
      bf16x8 t = *reinterpret_cast<const bf16x8*>(qp + kk * 32);
#pragma unroll
      for (int e = 0; e < 8; e++) t[e] = (__bf16)((float)t[e] * SCL);
      qf[mi][kk] = t;
    }
  }

  f32x4 ov[2][8];
#pragma unroll
  for (int mi = 0; mi < 2; mi++)
#pragma unroll
    for (int n = 0; n < 8; n++) {
      ov[mi][n][0] = 0.f; ov[mi][n][1] = 0.f; ov[mi][n][2] = 0.f; ov[mi][n][3] = 0.f;
    }
  float m[2], ssum[2];
  m[0] = -3.0e38f; m[1] = -3.0e38f;
  ssum[0] = 0.f; ssum[1] = 0.f;

  int nt = 4 * qblk + 4;
  bf16x8 kr0, kr1, vr0, vr1;

  kr0 = *reinterpret_cast<const bf16x8*>(kg);
  kr1 = *reinterpret_cast<const bf16x8*>(kg + 8);
  vr0 = *reinterpret_cast<const bf16x8*>(vg);
  vr1 = *reinterpret_cast<const bf16x8*>(vg + 8);
  *reinterpret_cast<bf16x8*>(KsB + koff0) = kr0;
  *reinterpret_cast<bf16x8*>(KsB + koff1) = kr1;
  *reinterpret_cast<bf16x8*>(VsB + voff0) = vr0;
  *reinterpret_cast<bf16x8*>(VsB + voff1) = vr1;
  __syncthreads();

  for (int t = 0;; t++) {
    int kv0 = t * 64;
    bool more = (t + 1 < nt);
    if (more) {
      int kvn = kv0 + 64;
      kr0 = *reinterpret_cast<const bf16x8*>(kg + (size_t)kvn * QKVW);
      kr1 = *reinterpret_cast<const bf16x8*>(kg + (size_t)kvn * QKVW + 8);
      vr0 = *reinterpret_cast<const bf16x8*>(vg + kvn);
      vr1 = *reinterpret_cast<const bf16x8*>(vg + kvn + 8);
    }

    bool active = (kv0 <= q0w + 31);
    if (active) {
      // ---- swapped QK^T: sc[mi][c] = S^T tile (rows=kv, cols=q)
      f32x4 sc[2][4];
#pragma unroll
      for (int mi = 0; mi < 2; mi++)
#pragma unroll
        for (int c = 0; c < 4; c++) {
          sc[mi][c][0] = 0.f; sc[mi][c][1] = 0.f; sc[mi][c][2] = 0.f; sc[mi][c][3] = 0.f;
        }
#pragma unroll
      for (int c = 0; c < 4; c++) {
        int rb = (c * 16 + lrow) * 256;
#pragma unroll
        for (int kk = 0; kk < 4; kk++) {
          bf16x8 kf = *reinterpret_cast<const bf16x8*>(KsB + rb + ((kk * 64 + lg * 16) ^ sw));
          sc[0][c] = mfma16(kf, qf[0][kk], sc[0][c]);
          sc[1][c] = mfma16(kf, qf[1][kk], sc[1][c]);
        }
      }

      // ---- causal mask: kv = kv0 + c*16 + lg*4 + jj ; q = q0w + mi*16 + lrow
      bool bound = (kv0 + 64 > q0w);
      if (bound) {
#pragma unroll
        for (int mi = 0; mi < 2; mi++) {
          int qidx = q0w + mi * 16 + lrow;
#pragma unroll
          for (int jj = 0; jj < 4; jj++) {
            int kvb = kv0 + lg * 4 + jj;
            if (kvb > qidx)      sc[mi][0][jj] = -3.0e38f;
            if (kvb + 16 > qidx) sc[mi][1][jj] = -3.0e38f;
            if (kvb + 32 > qidx) sc[mi][2][jj] = -3.0e38f;
            if (kvb + 48 > qidx) sc[mi][3][jj] = -3.0e38f;
          }
        }
      }

      // ---- per-lane growth check (all 16 values in-lane belong to q=lrow)
      float lm[2];
      bool lanegrow = false;
#pragma unroll
      for (int mi = 0; mi < 2; mi++) {
        float a0 = fmaxf(fmaxf(sc[mi][0][0], sc[mi][0][1]), fmaxf(sc[mi][0][2], sc[mi][0][3]));
        float a1 = fmaxf(fmaxf(sc[mi][1][0], sc[mi][1][1]), fmaxf(sc[mi][1][2], sc[mi][1][3]));
        float a2 = fmaxf(fmaxf(sc[mi][2][0], sc[mi][2][1]), fmaxf(sc[mi][2][2], sc[mi][2][3]));
        float a3 = fmaxf(fmaxf(sc[mi][3][0], sc[mi][3][1]), fmaxf(sc[mi][3][2], sc[mi][3][3]));
        lm[mi] = fmaxf(fmaxf(a0, a1), fmaxf(a2, a3));
        lanegrow |= (lm[mi] > m[mi] + 8.0f);
      }

      if (__any(lanegrow)) {
        // rare slow path: reduce row max over the 4 lg lanes, rescale
        float es[2];
#pragma unroll
        for (int mi = 0; mi < 2; mi++) {
          float r = lm[mi];
          r = fmaxf(r, __shfl_xor(r, 16));
          r = fmaxf(r, __shfl_xor(r, 32));
          float mo = m[mi];
          bool grow = (r > mo + 8.0f);
          float mn = grow ? r : mo;
          float e = grow ? exp2f(mo - r) : 1.0f;
          es[mi] = e;
          m[mi] = mn;
          ssum[mi] *= e;
        }
        // redistribute: ov rows are q=lg*4+jj, es lives at q=lrow lanes
        float esv[2][4];
#pragma unroll
        for (int mi = 0; mi < 2; mi++)
#pragma unroll
          for (int jj = 0; jj < 4; jj++)
            esv[mi][jj] = __shfl(es[mi], lg * 4 + jj);
#pragma unroll
        for (int mi = 0; mi < 2; mi++)
#pragma unroll
          for (int n = 0; n < 8; n++)
#pragma unroll
            for (int jj = 0; jj < 4; jj++) ov[mi][n][jj] *= esv[mi][jj];
      }

      // ---- exp2 + in-register P pack (pi order): pa[mi][c>>1][(r<<1)|(c&1)]
      bf16x8 pa[2][2];
#pragma unroll
      for (int mi = 0; mi < 2; mi++) {
        float mn = m[mi];
#pragma unroll
        for (int c = 0; c < 4; c++)
#pragma unroll
          for (int r = 0; r < 4; r++) {
            float p = exp2f(sc[mi][c][r] - mn);
            ssum[mi] += p;
            pa[mi][c >> 1][(r << 1) | (c & 1)] = (__bf16)p;
          }
      }

      // ---- PV: A = pa (in-register), B = pi-permuted V^T from LDS
#pragma unroll
      for (int kvs = 0; kvs < 2; kvs++) {
#pragma unroll
        for (int n = 0; n < 8; n++) {
          bf16x8 vf = *reinterpret_cast<const bf16x8*>(
              VsB + (n * 16 + lrow) * 128 + ((kvs * 64 + lg * 16) ^ sw));
          ov[0][n] = mfma16(pa[0][kvs], vf, ov[0][n]);
          ov[1][n] = mfma16(pa[1][kvs], vf, ov[1][n]);
        }
      }
    }

    if (!more) break;
    __syncthreads();
    *reinterpret_cast<bf16x8*>(KsB + koff0) = kr0;
    *reinterpret_cast<bf16x8*>(KsB + koff1) = kr1;
    *reinterpret_cast<bf16x8*>(VsB + voff0) = vr0;
    *reinterpret_cast<bf16x8*>(VsB + voff1) = vr1;
    __syncthreads();
  }

  // ---- epilogue: reduce ssum over lg, redistribute to ov's q-mapping, store
  float rs[2];
#pragma unroll
  for (int mi = 0; mi < 2; mi++) {
    float s = ssum[mi];
    s += __shfl_xor(s, 16);
    s += __shfl_xor(s, 32);
    rs[mi] = s;
  }
  float rinv[2][4];
#pragma unroll
  for (int mi = 0; mi < 2; mi++)
#pragma unroll
    for (int jj = 0; jj < 4; jj++)
      rinv[mi][jj] = 1.0f / __shfl(rs[mi], lg * 4 + jj);
#pragma unroll
  for (int mi = 0; mi < 2; mi++)
#pragma unroll
    for (int n = 0; n < 8; n++)
#pragma unroll
      for (int jj = 0; jj < 4; jj++) {
        out[(size_t)(b * S_LEN + q0w + mi * 16 + lg * 4 + jj) * HIDDEN + h * HD + n * 16 + lrow] =
            (__bf16)(ov[mi][n][jj] * rinv[mi][jj]);
      }
}

// ---------------------------------------------------------------------------
// Workspace layout (bytes), total 142606336:
//   h_bf / a_buf (aliased) @ 0          33554432   bf16 [4096][4096]
//   Wt (qkv^T, later Wo^T) @ 33554432   50331648   bf16 [6144][4096]
//   qkv_buf                @ 83886080   50331648   bf16 [4096][6144]
//   vt_buf                 @ 134217728   8388608   bf16 [16][128][2048]
// ---------------------------------------------------------------------------
extern "C" void kernel_launch(void* const* d_in, const int* in_sizes, int n_in,
                              void* d_out, int out_size, void* d_ws, size_t ws_size,
                              hipStream_t stream) {
  const float* hidden = (const float*)d_in[0];
  const int* posids   = (const int*)d_in[1];
  const float* Wq     = (const float*)d_in[2];
  const float* Wk     = (const float*)d_in[3];
  const float* Wv     = (const float*)d_in[4];
  const float* Wo     = (const float*)d_in[5];
  float* out = (float*)d_out;

  char* ws = (char*)d_ws;
  __bf16* h_bf    = (__bf16*)(ws + 0);
  __bf16* a_buf   = h_bf;  // aliased: h last read by QKV GEMMs, before attn writes
  __bf16* Wt      = (__bf16*)(ws + 33554432);
  __bf16* qkv_buf = (__bf16*)(ws + 83886080);
  __bf16* vt_buf  = (__bf16*)(ws + 134217728);

  dim3 b256(256), b328(32, 8), b512(512);

  // 1. hidden -> bf16
  cvt_kernel<<<dim3(MROWS * HIDDEN / (256 * 8)), b256, 0, stream>>>(hidden, h_bf, MROWS * HIDDEN);

  // 2. fused weight transpose: Wt = [Wq^T ; Wk^T ; Wv^T]  [6144][4096]
  tcvt3_kernel<<<dim3(128, 128, 3), b328, 0, stream>>>(Wq, Wk, Wv, Wt);

  // 3a. QKV main: cols [0,4096) via 256^2 tiles -> 256 blocks (1 round)
  gemm256<__bf16><<<dim3(256), b512, 0, stream>>>(
      h_bf, Wt, qkv_buf, HIDDEN, QKVW, 4096 / 256);
  // 3b. QKV tail: cols [4096,6144) via 256x128 tiles -> 256 blocks
  gemm128<__bf16><<<dim3(256), b512, 0, stream>>>(
      h_bf, Wt + (size_t)4096 * 4096, qkv_buf + 4096, HIDDEN, QKVW, 2048 / 128);

  // 4. RoPE on q,k (in fused buffer), vectorized
  rope_kernel<<<dim3(MROWS), b256, 0, stream>>>(qkv_buf, posids);

  // 5. V^T (pi-permuted kv within each 64-tile)
  tvt_kernel<<<dim3(HD / 32, S_LEN / 32, BATCH * NKV), b328, 0, stream>>>(qkv_buf, vt_buf);

  // 6. attention -> a_buf  (512 blocks, heavy-first)
  attn_kernel<<<dim3(8 * NH * BATCH), b512, 0, stream>>>(qkv_buf, vt_buf, a_buf);

  // 7. Wo^T (reuse Wt)
  tcvt_f32<<<dim3(HIDDEN / 32, HIDDEN / 32), b328, 0, stream>>>(Wo, Wt, HIDDEN, HIDDEN);

  // 8. out = a @ Wo  (fp32 out; 256 blocks = 1 balanced round)
  gemm256<float><<<dim3(256), b512, 0, stream>>>(
      a_buf, Wt, out, HIDDEN, HIDDEN, HIDDEN / 256);
}

// Round 14
// 459.030 us; speedup vs baseline: 1.8468x; 1.0029x over previous
//
#include <hip/hip_runtime.h>
#include <hip/hip_bf16.h>
#include <math.h>

#define HIDDEN 4096
#define NH 32
#define NKV 8
#define HD 128
#define S_LEN 2048
#define BATCH 2
#define MROWS (BATCH * S_LEN)  // 4096
#define QKVW 6144              // fused q|k|v row width

typedef __attribute__((ext_vector_type(8))) __bf16 bf16x8;
typedef __attribute__((ext_vector_type(4))) float f32x4;

__device__ __forceinline__ f32x4 mfma16(bf16x8 a, bf16x8 b, f32x4 c) {
  return __builtin_amdgcn_mfma_f32_16x16x32_bf16(a, b, c, 0, 0, 0);
}

// async global->LDS, 16B/lane; LDS dest = wave-uniform base, HW adds lane*16.
__device__ __forceinline__ void gload16(const __bf16* g, const __bf16* l) {
  __builtin_amdgcn_global_load_lds(
      (const __attribute__((address_space(1))) void*)g,
      (__attribute__((address_space(3))) void*)l, 16, 0, 0);
}

// De-pinned barriers (m141 lesson: sched_barrier(0) order-pinning defeats the
// compiler scheduler). asm("" ::: "memory") is a compiler-only fence: memory
// ops (gload_lds, ds_read) cannot cross the barrier, but VALU/MFMA/address
// scheduling stays free. vmcnt asm keeps its own memory clobber.
#define SBAR()                              \
  do {                                      \
    asm volatile("" ::: "memory");          \
    __builtin_amdgcn_s_barrier();           \
    asm volatile("" ::: "memory");          \
  } while (0)

#define VMCNT8() asm volatile("s_waitcnt vmcnt(8)" ::: "memory")
#define VMCNT6() asm volatile("s_waitcnt vmcnt(6)" ::: "memory")

// ---------------------------------------------------------------------------
// fp32 -> bf16 elementwise convert (vectorized)
// ---------------------------------------------------------------------------
__global__ __launch_bounds__(256) void cvt_kernel(const float* __restrict__ in,
                                                  __bf16* __restrict__ out, int n) {
  int i = (blockIdx.x * 256 + threadIdx.x) * 8;
  if (i >= n) return;
  float4 a = *reinterpret_cast<const float4*>(in + i);
  float4 b = *reinterpret_cast<const float4*>(in + i + 4);
  bf16x8 t;
  t[0] = (__bf16)a.x; t[1] = (__bf16)a.y; t[2] = (__bf16)a.z; t[3] = (__bf16)a.w;
  t[4] = (__bf16)b.x; t[5] = (__bf16)b.y; t[6] = (__bf16)b.z; t[7] = (__bf16)b.w;
  *reinterpret_cast<bf16x8*>(out + i) = t;
}

// ---------------------------------------------------------------------------
// Fused weight transpose+convert: z=0 Wq (4096 cols), z=1 Wk, z=2 Wv (1024).
// ---------------------------------------------------------------------------
__global__ __launch_bounds__(256) void tcvt3_kernel(const float* __restrict__ Wq,
                                                    const float* __restrict__ Wk,
                                                    const float* __restrict__ Wv,
                                                    __bf16* __restrict__ Wt) {
  __shared__ float t[32][33];
  int z = blockIdx.z;
  const float* in;
  __bf16* out;
  int C;
  if (z == 0)      { in = Wq; out = Wt;                         C = 4096; }
  else if (z == 1) { in = Wk; out = Wt + (size_t)4096 * 4096;   C = 1024; }
  else             { in = Wv; out = Wt + (size_t)5120 * 4096;   C = 1024; }
  if ((int)blockIdx.x * 32 >= C) return;
  int tx = threadIdx.x, ty = threadIdx.y;
  int r0 = blockIdx.y * 32, c0 = blockIdx.x * 32;
#pragma unroll
  for (int i = 0; i < 4; i++)
    t[ty + i * 8][tx] = in[(size_t)(r0 + ty + i * 8) * C + c0 + tx];
  __syncthreads();
#pragma unroll
  for (int i = 0; i < 4; i++)
    out[(size_t)(c0 + ty + i * 8) * 4096 + r0 + tx] = (__bf16)t[tx][ty + i * 8];
}

// single transpose for Wo
__global__ __launch_bounds__(256) void tcvt_f32(const float* __restrict__ in,
                                                __bf16* __restrict__ out,
                                                int R, int C) {
  __shared__ float t[32][33];
  int tx = threadIdx.x, ty = threadIdx.y;
  int r0 = blockIdx.y * 32, c0 = blockIdx.x * 32;
#pragma unroll
  for (int i = 0; i < 4; i++)
    t[ty + i * 8][tx] = in[(size_t)(r0 + ty + i * 8) * C + c0 + tx];
  __syncthreads();
#pragma unroll
  for (int i = 0; i < 4; i++)
    out[(size_t)(c0 + ty + i * 8) * R + r0 + tx] = (__bf16)t[tx][ty + i * 8];
}

// ---------------------------------------------------------------------------
// V transpose: qkv -> vt [B*NKV][HD][S], with pair-interleave permutation
// pi(16a+r) = 32*(a>>1) + 2r + (a&1) applied WITHIN each 64-kv tile.
// ---------------------------------------------------------------------------
__global__ __launch_bounds__(256) void tvt_kernel(const __bf16* __restrict__ qkv,
                                                  __bf16* __restrict__ vt) {
  __shared__ __bf16 t[32][33];
  int tx = threadIdx.x, ty = threadIdx.y;
  int z = blockIdx.z;
  int b = z >> 3, kvh = z & 7;
  int kv0 = blockIdx.y * 32, d0 = blockIdx.x * 32;
#pragma unroll
  for (int i = 0; i < 4; i++)
    t[ty + i * 8][tx] =
        qkv[(size_t)(b * S_LEN + kv0 + ty + i * 8) * QKVW + 5120 + kvh * HD + d0 + tx];
  __syncthreads();
  int cperm = kv0 + 2 * (tx & 15) + (tx >> 4);
#pragma unroll
  for (int i = 0; i < 4; i++)
    vt[((size_t)z * HD + d0 + ty + i * 8) * S_LEN + cperm] = t[tx][ty + i * 8];
}

// ---------------------------------------------------------------------------
// 256x256 GEMM, deep-pipelined, de-pinned barriers (this round's change).
// ---------------------------------------------------------------------------
template<typename CT>
__global__ __launch_bounds__(512, 2) void gemm256(const __bf16* __restrict__ A,
                                                  const __bf16* __restrict__ Bt,
                                                  CT* __restrict__ C,
                                                  int K, int ldc, int nbx) {
  __shared__ char lds[131072];
  const int tid = threadIdx.x;
  const int l = tid & 63, w = tid >> 6;
  const int lrow = l & 15, lg = l >> 4;
  const int sw = (lrow & 7) << 4;

  int nwg = gridDim.x;
  int swz = (blockIdx.x & 7) * (nwg >> 3) + (blockIdx.x >> 3);
  int bx = swz % nbx, by = swz / nbx;
  int m0 = by * 256, n0 = bx * 256;

  const int rA = w * 8 + (l >> 3);
  const int csw = ((l & 7) ^ (l >> 3)) * 8;  // inverse-swizzled source col
  const __bf16* As_[2][2];
  const __bf16* Bs_[2][2];
#pragma unroll
  for (int h = 0; h < 2; h++)
#pragma unroll
    for (int p = 0; p < 2; p++) {
      As_[h][p] = A + (size_t)(m0 + h * 128 + p * 64 + rA) * K + csw;
      Bs_[h][p] = Bt + (size_t)(n0 + h * 128 + p * 64 + rA) * K + csw;
    }

  auto stageA = [&](int par, int h, int kt) {
#pragma unroll
    for (int p = 0; p < 2; p++)
      gload16(As_[h][p] + kt * 64,
              (const __bf16*)(lds + par * 32768 + h * 16384 + p * 8192 + w * 1024));
  };
  auto stageB = [&](int par, int h, int kt) {
#pragma unroll
    for (int p = 0; p < 2; p++)
      gload16(Bs_[h][p] + kt * 64,
              (const __bf16*)(lds + 65536 + par * 32768 + h * 16384 + p * 8192 + w * 1024));
  };

  const int arbase = (w >> 2) * 64 + lrow;
  const int brbase = (w & 3) * 32 + lrow;

  bf16x8 aA[4][2];
  bf16x8 bB[2][2][2];

  auto readA = [&](int par, int ah) {
#pragma unroll
    for (int i = 0; i < 4; i++)
#pragma unroll
      for (int kk = 0; kk < 2; kk++)
        aA[i][kk] = *reinterpret_cast<const bf16x8*>(
            lds + par * 32768 + (arbase + i * 16 + ah * 128) * 128 +
            ((kk * 64 + lg * 16) ^ sw));
  };
  auto readB = [&](int par, int bh) {
#pragma unroll
    for (int j = 0; j < 2; j++)
#pragma unroll
      for (int kk = 0; kk < 2; kk++)
        bB[bh][j][kk] = *reinterpret_cast<const bf16x8*>(
            lds + 65536 + par * 32768 + (brbase + j * 16 + bh * 128) * 128 +
            ((kk * 64 + lg * 16) ^ sw));
  };

  f32x4 acc[8][4];
#pragma unroll
  for (int i = 0; i < 8; i++)
#pragma unroll
    for (int j = 0; j < 4; j++) {
      acc[i][j][0] = 0.f; acc[i][j][1] = 0.f; acc[i][j][2] = 0.f; acc[i][j][3] = 0.f;
    }

  const int NT = K >> 6;

  stageA(0, 0, 0); stageB(0, 0, 0);
  stageA(0, 1, 0); stageB(0, 1, 0);
  stageA(1, 0, 1); stageB(1, 0, 1);
  VMCNT8();
  SBAR();

#define MFMA_QUAD(AH, BH)                                                   \
  __builtin_amdgcn_s_setprio(1);                                            \
  _Pragma("unroll") for (int i4 = 0; i4 < 4; i4++)                          \
      _Pragma("unroll") for (int j2 = 0; j2 < 2; j2++)                      \
          _Pragma("unroll") for (int kk = 0; kk < 2; kk++)                  \
              acc[(AH)*4 + i4][(BH)*2 + j2] =                               \
                  mfma16(aA[i4][kk], bB[BH][j2][kk], acc[(AH)*4 + i4][(BH)*2 + j2]); \
  __builtin_amdgcn_s_setprio(0);

#define GTILE256(PAR, TT)                                                   \
  {                                                                         \
    const int t1n = ((TT) + 1 < NT) ? (TT) + 1 : 0;                         \
    const int t2n = ((TT) + 2 < NT) ? (TT) + 2 : 0;                         \
    readA(PAR, 0);                                                          \
    readB(PAR, 0);                                                          \
    stageA(PAR ^ 1, 1, t1n);                                                \
    stageB(PAR ^ 1, 1, t1n);                                                \
    VMCNT8();                                                               \
    SBAR();                                                                 \
    MFMA_QUAD(0, 0);                                                        \
    SBAR();                                                                 \
    readB(PAR, 1);                                                          \
    stageA(PAR, 0, t2n);                                                    \
    SBAR();                                                                 \
    MFMA_QUAD(0, 1);                                                        \
    SBAR();                                                                 \
    readA(PAR, 1);                                                          \
    stageB(PAR, 0, t2n);                                                    \
    SBAR();                                                                 \
    MFMA_QUAD(1, 0);                                                        \
    MFMA_QUAD(1, 1);                                                        \
    VMCNT8();                                                               \
    SBAR();                                                                 \
  }

  for (int t = 0; t < NT; t += 2) {
    GTILE256(0, t);
    GTILE256(1, t + 1);
  }
#undef GTILE256
#undef MFMA_QUAD

#pragma unroll
  for (int i = 0; i < 8; i++) {
    int row = m0 + (w >> 2) * 64 + (i & 3) * 16 + (i >> 2) * 128 + lg * 4;
#pragma unroll
    for (int j = 0; j < 4; j++) {
      int col = n0 + (w & 3) * 32 + (j & 1) * 16 + (j >> 1) * 128 + lrow;
#pragma unroll
      for (int jj = 0; jj < 4; jj++)
        C[(size_t)(row + jj) * ldc + col] = (CT)acc[i][j][jj];
    }
  }
}

// ---------------------------------------------------------------------------
// 256x128 GEMM, deep-pipelined, de-pinned barriers.
// ---------------------------------------------------------------------------
template<typename CT>
__global__ __launch_bounds__(512, 2) void gemm128(const __bf16* __restrict__ A,
                                                  const __bf16* __restrict__ Bt,
                                                  CT* __restrict__ C,
                                                  int K, int ldc, int nbx) {
  __shared__ char lds[98304];
  const int tid = threadIdx.x;
  const int l = tid & 63, w = tid >> 6;
  const int lrow = l & 15, lg = l >> 4;
  const int sw = (lrow & 7) << 4;

  int nwg = gridDim.x;
  int swz = (blockIdx.x & 7) * (nwg >> 3) + (blockIdx.x >> 3);
  int bx = swz % nbx, by = swz / nbx;
  int m0 = by * 256, n0 = bx * 128;

  const int rA = w * 8 + (l >> 3);
  const int csw = ((l & 7) ^ (l >> 3)) * 8;
  const __bf16* As_[2][2];
  const __bf16* Bs_[2];
#pragma unroll
  for (int h = 0; h < 2; h++)
#pragma unroll
    for (int p = 0; p < 2; p++)
      As_[h][p] = A + (size_t)(m0 + h * 128 + p * 64 + rA) * K + csw;
#pragma unroll
  for (int p = 0; p < 2; p++)
    Bs_[p] = Bt + (size_t)(n0 + p * 64 + rA) * K + csw;

  auto stageA = [&](int par, int h, int kt) {
#pragma unroll
    for (int p = 0; p < 2; p++)
      gload16(As_[h][p] + kt * 64,
              (const __bf16*)(lds + par * 32768 + h * 16384 + p * 8192 + w * 1024));
  };
  auto stageB = [&](int par, int kt) {
#pragma unroll
    for (int p = 0; p < 2; p++)
      gload16(Bs_[p] + kt * 64,
              (const __bf16*)(lds + 65536 + par * 16384 + p * 8192 + w * 1024));
  };

  const int arbase = (w >> 2) * 64 + lrow;
  const int brbase = (w & 3) * 32 + lrow;

  bf16x8 aA[4][2];
  bf16x8 bB[2][2];

  auto readA = [&](int par, int ah) {
#pragma unroll
    for (int i = 0; i < 4; i++)
#pragma unroll
      for (int kk = 0; kk < 2; kk++)
        aA[i][kk] = *reinterpret_cast<const bf16x8*>(
            lds + par * 32768 + (arbase + i * 16 + ah * 128) * 128 +
            ((kk * 64 + lg * 16) ^ sw));
  };
  auto readB = [&](int par) {
#pragma unroll
    for (int j = 0; j < 2; j++)
#pragma unroll
      for (int kk = 0; kk < 2; kk++)
        bB[j][kk] = *reinterpret_cast<const bf16x8*>(
            lds + 65536 + par * 16384 + (brbase + j * 16) * 128 +
            ((kk * 64 + lg * 16) ^ sw));
  };

  f32x4 acc[8][2];
#pragma unroll
  for (int i = 0; i < 8; i++)
#pragma unroll
    for (int j = 0; j < 2; j++) {
      acc[i][j][0] = 0.f; acc[i][j][1] = 0.f; acc[i][j][2] = 0.f; acc[i][j][3] = 0.f;
    }

  const int NT = K >> 6;

  stageA(0, 0, 0); stageB(0, 0);
  stageA(0, 1, 0); stageB(1, 1); stageA(1, 0, 1);
  VMCNT6();
  SBAR();

#define MFMA_HALF(AH)                                                        \
  __builtin_amdgcn_s_setprio(1);                                             \
  _Pragma("unroll") for (int i4 = 0; i4 < 4; i4++)                           \
      _Pragma("unroll") for (int j2 = 0; j2 < 2; j2++)                       \
          _Pragma("unroll") for (int kk = 0; kk < 2; kk++)                   \
              acc[(AH)*4 + i4][j2] =                                         \
                  mfma16(aA[i4][kk], bB[j2][kk], acc[(AH)*4 + i4][j2]);      \
  __builtin_amdgcn_s_setprio(0);

#define GTILE128(PAR, TT)                                                    \
  {                                                                          \
    const int t1n = ((TT) + 1 < NT) ? (TT) + 1 : 0;                          \
    const int t2n = ((TT) + 2 < NT) ? (TT) + 2 : 0;                          \
    readA(PAR, 0);                                                           \
    readB(PAR);                                                              \
    stageA(PAR ^ 1, 1, t1n);                                                 \
    VMCNT6();                                                                \
    SBAR();                                                                  \
    MFMA_HALF(0);                                                            \
    SBAR();                                                                  \
    readA(PAR, 1);                                                           \
    stageB(PAR, t2n);                                                        \
    stageA(PAR, 0, t2n);                                                     \
    SBAR();                                                                  \
    MFMA_HALF(1);                                                            \
    VMCNT6();                                                                \
    SBAR();                                                                  \
  }

  for (int t = 0; t < NT; t += 2) {
    GTILE128(0, t);
    GTILE128(1, t + 1);
  }
#undef GTILE128
#undef MFMA_HALF

#pragma unroll
  for (int i = 0; i < 8; i++) {
    int row = m0 + (w >> 2) * 64 + (i & 3) * 16 + (i >> 2) * 128 + lg * 4;
#pragma unroll
    for (int j = 0; j < 2; j++) {
      int col = n0 + (w & 3) * 32 + j * 16 + lrow;
#pragma unroll
      for (int jj = 0; jj < 4; jj++)
        C[(size_t)(row + jj) * ldc + col] = (CT)acc[i][j][jj];
    }
  }
}

// ---------------------------------------------------------------------------
// RoPE, in-place on fused qkv buffer, vectorized.
// ---------------------------------------------------------------------------
__global__ __launch_bounds__(256) void rope_kernel(__bf16* __restrict__ qkv,
                                                   const int* __restrict__ pos) {
  int row = blockIdx.x;
  int t = threadIdx.x;
  float p = (float)pos[row];
  __bf16* rbase = qkv + (size_t)row * QKVW;

  {
    int head = t >> 3, chunk = t & 7;
    __bf16* base = rbase + head * HD + chunk * 8;
    bf16x8 x1 = *reinterpret_cast<const bf16x8*>(base);
    bf16x8 x2 = *reinterpret_cast<const bf16x8*>(base + 64);
    bf16x8 o1, o2;
#pragma unroll
    for (int e = 0; e < 8; e++) {
      float ang = p * exp2f(-0.20762050f * (float)(chunk * 8 + e));
      float s, c;
      __sincosf(ang, &s, &c);
      float a = (float)x1[e], b2 = (float)x2[e];
      o1[e] = (__bf16)(a * c - b2 * s);
      o2[e] = (__bf16)(b2 * c + a * s);
    }
    *reinterpret_cast<bf16x8*>(base) = o1;
    *reinterpret_cast<bf16x8*>(base + 64) = o2;
  }
  if (t < 64) {
    int head = t >> 3, chunk = t & 7;
    __bf16* base = rbase + 4096 + head * HD + chunk * 8;
    bf16x8 x1 = *reinterpret_cast<const bf16x8*>(base);
    bf16x8 x2 = *reinterpret_cast<const bf16x8*>(base + 64);
    bf16x8 o1, o2;
#pragma unroll
    for (int e = 0; e < 8; e++) {
      float ang = p * exp2f(-0.20762050f * (float)(chunk * 8 + e));
      float s, c;
      __sincosf(ang, &s, &c);
      float a = (float)x1[e], b2 = (float)x2[e];
      o1[e] = (__bf16)(a * c - b2 * s);
      o2[e] = (__bf16)(b2 * c + a * s);
    }
    *reinterpret_cast<bf16x8*>(base) = o1;
    *reinterpret_cast<bf16x8*>(base + 64) = o2;
  }
}

// ---------------------------------------------------------------------------
// Flash attention, causal, GQA (R13 structure, unchanged). Swapped QK^T,
// in-register pi-packed P, guarded reduce, plain __launch_bounds__(512).
// ---------------------------------------------------------------------------
__global__ __launch_bounds__(512) void attn_kernel(const __bf16* __restrict__ qkv,
                                                   const __bf16* __restrict__ vt,
                                                   __bf16* __restrict__ out) {
  __shared__ __bf16 Ks[64 * 128];      // [kv][d], swizzled, 16 KB
  __shared__ __bf16 Vs[128 * 64];      // [d][kv'], swizzled, 16 KB

  int tid = threadIdx.x;
  int l = tid & 63, w = tid >> 6;
  int bid = blockIdx.x;
  int qblk = 7 - (bid >> 6);           // heavy blocks first
  int rem = bid & 63;
  int h = rem & 31, b = rem >> 5;
  int kvh = h >> 2;
  int q0w = qblk * 256 + w * 32;
  int lrow = l & 15, lg = l >> 4;
  int sw = (lrow & 7) << 4;
  const float SCL = 0.08838834764831845f * 1.4426950408889634f;  // 1/sqrt(128)*log2e

  const __bf16* kbase = qkv + (size_t)(b * S_LEN) * QKVW + 4096 + kvh * HD;
  const __bf16* vbase = vt + ((size_t)(b * NKV + kvh) * HD) * S_LEN;

  int krow = tid >> 3;
  int kslot = (tid & 7) * 2;
  int vrow = tid >> 2;
  int vslot = (tid & 3) * 2;
  char* KsB = (char*)Ks;
  char* VsB = (char*)Vs;
  int koff0 = krow * 256 + ((kslot * 16) ^ ((krow & 7) << 4));
  int koff1 = krow * 256 + (((kslot + 1) * 16) ^ ((krow & 7) << 4));
  int voff0 = vrow * 128 + ((vslot * 16) ^ ((vrow & 7) << 4));
  int voff1 = vrow * 128 + (((vslot + 1) * 16) ^ ((vrow & 7) << 4));
  const __bf16* kg = kbase + (size_t)krow * QKVW + kslot * 8;
  const __bf16* vg = vbase + (size_t)vrow * S_LEN + vslot * 8;

  // Q fragments, pre-scaled (per-lane data doubles as the MFMA B-operand)
  bf16x8 qf[2][4];
#pragma unroll
  for (int mi = 0; mi < 2; mi++) {
    const __bf16* qp = qkv + (size_t)(b * S_LEN + q0w + mi * 16 + lrow) * QKVW + h * HD + lg * 8;
#pragma unroll
    for (int kk = 0; kk < 4; kk++) {
      bf16x8 t = *reinterpret_cast<const bf16x8*>(qp + kk * 32);
#pragma unroll
      for (int e = 0; e < 8; e++) t[e] = (__bf16)((float)t[e] * SCL);
      qf[mi][kk] = t;
    }
  }

  f32x4 ov[2][8];
#pragma unroll
  for (int mi = 0; mi < 2; mi++)
#pragma unroll
    for (int n = 0; n < 8; n++) {
      ov[mi][n][0] = 0.f; ov[mi][n][1] = 0.f; ov[mi][n][2] = 0.f; ov[mi][n][3] = 0.f;
    }
  float m[2], ssum[2];
  m[0] = -3.0e38f; m[1] = -3.0e38f;
  ssum[0] = 0.f; ssum[1] = 0.f;

  int nt = 4 * qblk + 4;
  bf16x8 kr0, kr1, vr0, vr1;

  kr0 = *reinterpret_cast<const bf16x8*>(kg);
  kr1 = *reinterpret_cast<const bf16x8*>(kg + 8);
  vr0 = *reinterpret_cast<const bf16x8*>(vg);
  vr1 = *reinterpret_cast<const bf16x8*>(vg + 8);
  *reinterpret_cast<bf16x8*>(KsB + koff0) = kr0;
  *reinterpret_cast<bf16x8*>(KsB + koff1) = kr1;
  *reinterpret_cast<bf16x8*>(VsB + voff0) = vr0;
  *reinterpret_cast<bf16x8*>(VsB + voff1) = vr1;
  __syncthreads();

  for (int t = 0;; t++) {
    int kv0 = t * 64;
    bool more = (t + 1 < nt);
    if (more) {
      int kvn = kv0 + 64;
      kr0 = *reinterpret_cast<const bf16x8*>(kg + (size_t)kvn * QKVW);
      kr1 = *reinterpret_cast<const bf16x8*>(kg + (size_t)kvn * QKVW + 8);
      vr0 = *reinterpret_cast<const bf16x8*>(vg + kvn);
      vr1 = *reinterpret_cast<const bf16x8*>(vg + kvn + 8);
    }

    bool active = (kv0 <= q0w + 31);
    if (active) {
      // ---- swapped QK^T: sc[mi][c] = S^T tile (rows=kv, cols=q)
      f32x4 sc[2][4];
#pragma unroll
      for (int mi = 0; mi < 2; mi++)
#pragma unroll
        for (int c = 0; c < 4; c++) {
          sc[mi][c][0] = 0.f; sc[mi][c][1] = 0.f; sc[mi][c][2] = 0.f; sc[mi][c][3] = 0.f;
        }
#pragma unroll
      for (int c = 0; c < 4; c++) {
        int rb = (c * 16 + lrow) * 256;
#pragma unroll
        for (int kk = 0; kk < 4; kk++) {
          bf16x8 kf = *reinterpret_cast<const bf16x8*>(KsB + rb + ((kk * 64 + lg * 16) ^ sw));
          sc[0][c] = mfma16(kf, qf[0][kk], sc[0][c]);
          sc[1][c] = mfma16(kf, qf[1][kk], sc[1][c]);
        }
      }

      // ---- causal mask: kv = kv0 + c*16 + lg*4 + jj ; q = q0w + mi*16 + lrow
      bool bound = (kv0 + 64 > q0w);
      if (bound) {
#pragma unroll
        for (int mi = 0; mi < 2; mi++) {
          int qidx = q0w + mi * 16 + lrow;
#pragma unroll
          for (int jj = 0; jj < 4; jj++) {
            int kvb = kv0 + lg * 4 + jj;
            if (kvb > qidx)      sc[mi][0][jj] = -3.0e38f;
            if (kvb + 16 > qidx) sc[mi][1][jj] = -3.0e38f;
            if (kvb + 32 > qidx) sc[mi][2][jj] = -3.0e38f;
            if (kvb + 48 > qidx) sc[mi][3][jj] = -3.0e38f;
          }
        }
      }

      // ---- per-lane growth check (all 16 values in-lane belong to q=lrow)
      float lm[2];
      bool lanegrow = false;
#pragma unroll
      for (int mi = 0; mi < 2; mi++) {
        float a0 = fmaxf(fmaxf(sc[mi][0][0], sc[mi][0][1]), fmaxf(sc[mi][0][2], sc[mi][0][3]));
        float a1 = fmaxf(fmaxf(sc[mi][1][0], sc[mi][1][1]), fmaxf(sc[mi][1][2], sc[mi][1][3]));
        float a2 = fmaxf(fmaxf(sc[mi][2][0], sc[mi][2][1]), fmaxf(sc[mi][2][2], sc[mi][2][3]));
        float a3 = fmaxf(fmaxf(sc[mi][3][0], sc[mi][3][1]), fmaxf(sc[mi][3][2], sc[mi][3][3]));
        lm[mi] = fmaxf(fmaxf(a0, a1), fmaxf(a2, a3));
        lanegrow |= (lm[mi] > m[mi] + 8.0f);
      }

      if (__any(lanegrow)) {
        // rare slow path: reduce row max over the 4 lg lanes, rescale
        float es[2];
#pragma unroll
        for (int mi = 0; mi < 2; mi++) {
          float r = lm[mi];
          r = fmaxf(r, __shfl_xor(r, 16));
          r = fmaxf(r, __shfl_xor(r, 32));
          float mo = m[mi];
          bool grow = (r > mo + 8.0f);
          float mn = grow ? r : mo;
          float e = grow ? exp2f(mo - r) : 1.0f;
          es[mi] = e;
          m[mi] = mn;
          ssum[mi] *= e;
        }
        // redistribute: ov rows are q=lg*4+jj, es lives at q=lrow lanes
        float esv[2][4];
#pragma unroll
        for (int mi = 0; mi < 2; mi++)
#pragma unroll
          for (int jj = 0; jj < 4; jj++)
            esv[mi][jj] = __shfl(es[mi], lg * 4 + jj);
#pragma unroll
        for (int mi = 0; mi < 2; mi++)
#pragma unroll
          for (int n = 0; n < 8; n++)
#pragma unroll
            for (int jj = 0; jj < 4; jj++) ov[mi][n][jj] *= esv[mi][jj];
      }

      // ---- exp2 + in-register P pack (pi order): pa[mi][c>>1][(r<<1)|(c&1)]
      bf16x8 pa[2][2];
#pragma unroll
      for (int mi = 0; mi < 2; mi++) {
        float mn = m[mi];
#pragma unroll
        for (int c = 0; c < 4; c++)
#pragma unroll
          for (int r = 0; r < 4; r++) {
            float p = exp2f(sc[mi][c][r] - mn);
            ssum[mi] += p;
            pa[mi][c >> 1][(r << 1) | (c & 1)] = (__bf16)p;
          }
      }

      // ---- PV: A = pa (in-register), B = pi-permuted V^T from LDS
#pragma unroll
      for (int kvs = 0; kvs < 2; kvs++) {
#pragma unroll
        for (int n = 0; n < 8; n++) {
          bf16x8 vf = *reinterpret_cast<const bf16x8*>(
              VsB + (n * 16 + lrow) * 128 + ((kvs * 64 + lg * 16) ^ sw));
          ov[0][n] = mfma16(pa[0][kvs], vf, ov[0][n]);
          ov[1][n] = mfma16(pa[1][kvs], vf, ov[1][n]);
        }
      }
    }

    if (!more) break;
    __syncthreads();
    *reinterpret_cast<bf16x8*>(KsB + koff0) = kr0;
    *reinterpret_cast<bf16x8*>(KsB + koff1) = kr1;
    *reinterpret_cast<bf16x8*>(VsB + voff0) = vr0;
    *reinterpret_cast<bf16x8*>(VsB + voff1) = vr1;
    __syncthreads();
  }

  // ---- epilogue: reduce ssum over lg, redistribute to ov's q-mapping, store
  float rs[2];
#pragma unroll
  for (int mi = 0; mi < 2; mi++) {
    float s = ssum[mi];
    s += __shfl_xor(s, 16);
    s += __shfl_xor(s, 32);
    rs[mi] = s;
  }
  float rinv[2][4];
#pragma unroll
  for (int mi = 0; mi < 2; mi++)
#pragma unroll
    for (int jj = 0; jj < 4; jj++)
      rinv[mi][jj] = 1.0f / __shfl(rs[mi], lg * 4 + jj);
#pragma unroll
  for (int mi = 0; mi < 2; mi++)
#pragma unroll
    for (int n = 0; n < 8; n++)
#pragma unroll
      for (int jj = 0; jj < 4; jj++) {
        out[(size_t)(b * S_LEN + q0w + mi * 16 + lg * 4 + jj) * HIDDEN + h * HD + n * 16 + lrow] =
            (__bf16)(ov[mi][n][jj] * rinv[mi][jj]);
      }
}

// ---------------------------------------------------------------------------
// Workspace layout (bytes), total 142606336:
//   h_bf / a_buf (aliased) @ 0          33554432   bf16 [4096][4096]
//   Wt (qkv^T, later Wo^T) @ 33554432   50331648   bf16 [6144][4096]
//   qkv_buf                @ 83886080   50331648   bf16 [4096][6144]
//   vt_buf                 @ 134217728   8388608   bf16 [16][128][2048]
// ---------------------------------------------------------------------------
extern "C" void kernel_launch(void* const* d_in, const int* in_sizes, int n_in,
                              void* d_out, int out_size, void* d_ws, size_t ws_size,
                              hipStream_t stream) {
  const float* hidden = (const float*)d_in[0];
  const int* posids   = (const int*)d_in[1];
  const float* Wq     = (const float*)d_in[2];
  const float* Wk     = (const float*)d_in[3];
  const float* Wv     = (const float*)d_in[4];
  const float* Wo     = (const float*)d_in[5];
  float* out = (float*)d_out;

  char* ws = (char*)d_ws;
  __bf16* h_bf    = (__bf16*)(ws + 0);
  __bf16* a_buf   = h_bf;  // aliased: h last read by QKV GEMMs, before attn writes
  __bf16* Wt      = (__bf16*)(ws + 33554432);
  __bf16* qkv_buf = (__bf16*)(ws + 83886080);
  __bf16* vt_buf  = (__bf16*)(ws + 134217728);

  dim3 b256(256), b328(32, 8), b512(512);

  // 1. hidden -> bf16
  cvt_kernel<<<dim3(MROWS * HIDDEN / (256 * 8)), b256, 0, stream>>>(hidden, h_bf, MROWS * HIDDEN);

  // 2. fused weight transpose: Wt = [Wq^T ; Wk^T ; Wv^T]  [6144][4096]
  tcvt3_kernel<<<dim3(128, 128, 3), b328, 0, stream>>>(Wq, Wk, Wv, Wt);

  // 3a. QKV main: cols [0,4096) via 256^2 tiles -> 256 blocks (1 round)
  gemm256<__bf16><<<dim3(256), b512, 0, stream>>>(
      h_bf, Wt, qkv_buf, HIDDEN, QKVW, 4096 / 256);
  // 3b. QKV tail: cols [4096,6144) via 256x128 tiles -> 256 blocks
  gemm128<__bf16><<<dim3(256), b512, 0, stream>>>(
      h_bf, Wt + (size_t)4096 * 4096, qkv_buf + 4096, HIDDEN, QKVW, 2048 / 128);

  // 4. RoPE on q,k (in fused buffer), vectorized
  rope_kernel<<<dim3(MROWS), b256, 0, stream>>>(qkv_buf, posids);

  // 5. V^T (pi-permuted kv within each 64-tile)
  tvt_kernel<<<dim3(HD / 32, S_LEN / 32, BATCH * NKV), b328, 0, stream>>>(qkv_buf, vt_buf);

  // 6. attention -> a_buf  (512 blocks, heavy-first)
  attn_kernel<<<dim3(8 * NH * BATCH), b512, 0, stream>>>(qkv_buf, vt_buf, a_buf);

  // 7. Wo^T (reuse Wt)
  tcvt_f32<<<dim3(HIDDEN / 32, HIDDEN / 32), b328, 0, stream>>>(Wo, Wt, HIDDEN, HIDDEN);

  // 8. out = a @ Wo  (fp32 out; 256 blocks = 1 balanced round)
  gemm256<float><<<dim3(256), b512, 0, stream>>>(
      a_buf, Wt, out, HIDDEN, HIDDEN, HIDDEN / 256);
}

// Round 15
// 451.234 us; speedup vs baseline: 1.8787x; 1.0173x over previous
//
#include <hip/hip_runtime.h>
#include <hip/hip_bf16.h>
#include <math.h>

#define HIDDEN 4096
#define NH 32
#define NKV 8
#define HD 128
#define S_LEN 2048
#define BATCH 2
#define MROWS (BATCH * S_LEN)  // 4096
#define QKVW 6144              // fused q|k|v row width

typedef __attribute__((ext_vector_type(8))) __bf16 bf16x8;
typedef __attribute__((ext_vector_type(4))) float f32x4;

__device__ __forceinline__ f32x4 mfma16(bf16x8 a, bf16x8 b, f32x4 c) {
  return __builtin_amdgcn_mfma_f32_16x16x32_bf16(a, b, c, 0, 0, 0);
}

// async global->LDS, 16B/lane; LDS dest = wave-uniform base, HW adds lane*16.
__device__ __forceinline__ void gload16(const __bf16* g, const __bf16* l) {
  __builtin_amdgcn_global_load_lds(
      (const __attribute__((address_space(1))) void*)g,
      (__attribute__((address_space(3))) void*)l, 16, 0, 0);
}

// De-pinned barriers: compiler-only memory fence + raw s_barrier.
#define SBAR()                              \
  do {                                      \
    asm volatile("" ::: "memory");          \
    __builtin_amdgcn_s_barrier();           \
    asm volatile("" ::: "memory");          \
  } while (0)

#define VMCNT8() asm volatile("s_waitcnt vmcnt(8)" ::: "memory")
#define VMCNT6() asm volatile("s_waitcnt vmcnt(6)" ::: "memory")

// ---------------------------------------------------------------------------
// fp32 -> bf16 elementwise convert (vectorized)
// ---------------------------------------------------------------------------
__global__ __launch_bounds__(256) void cvt_kernel(const float* __restrict__ in,
                                                  __bf16* __restrict__ out, int n) {
  int i = (blockIdx.x * 256 + threadIdx.x) * 8;
  if (i >= n) return;
  float4 a = *reinterpret_cast<const float4*>(in + i);
  float4 b = *reinterpret_cast<const float4*>(in + i + 4);
  bf16x8 t;
  t[0] = (__bf16)a.x; t[1] = (__bf16)a.y; t[2] = (__bf16)a.z; t[3] = (__bf16)a.w;
  t[4] = (__bf16)b.x; t[5] = (__bf16)b.y; t[6] = (__bf16)b.z; t[7] = (__bf16)b.w;
  *reinterpret_cast<bf16x8*>(out + i) = t;
}

// ---------------------------------------------------------------------------
// Fused weight transpose+convert: z=0 Wq (4096 cols), z=1 Wk, z=2 Wv (1024).
// ---------------------------------------------------------------------------
__global__ __launch_bounds__(256) void tcvt3_kernel(const float* __restrict__ Wq,
                                                    const float* __restrict__ Wk,
                                                    const float* __restrict__ Wv,
                                                    __bf16* __restrict__ Wt) {
  __shared__ float t[32][33];
  int z = blockIdx.z;
  const float* in;
  __bf16* out;
  int C;
  if (z == 0)      { in = Wq; out = Wt;                         C = 4096; }
  else if (z == 1) { in = Wk; out = Wt + (size_t)4096 * 4096;   C = 1024; }
  else             { in = Wv; out = Wt + (size_t)5120 * 4096;   C = 1024; }
  if ((int)blockIdx.x * 32 >= C) return;
  int tx = threadIdx.x, ty = threadIdx.y;
  int r0 = blockIdx.y * 32, c0 = blockIdx.x * 32;
#pragma unroll
  for (int i = 0; i < 4; i++)
    t[ty + i * 8][tx] = in[(size_t)(r0 + ty + i * 8) * C + c0 + tx];
  __syncthreads();
#pragma unroll
  for (int i = 0; i < 4; i++)
    out[(size_t)(c0 + ty + i * 8) * 4096 + r0 + tx] = (__bf16)t[tx][ty + i * 8];
}

// single transpose for Wo
__global__ __launch_bounds__(256) void tcvt_f32(const float* __restrict__ in,
                                                __bf16* __restrict__ out,
                                                int R, int C) {
  __shared__ float t[32][33];
  int tx = threadIdx.x, ty = threadIdx.y;
  int r0 = blockIdx.y * 32, c0 = blockIdx.x * 32;
#pragma unroll
  for (int i = 0; i < 4; i++)
    t[ty + i * 8][tx] = in[(size_t)(r0 + ty + i * 8) * C + c0 + tx];
  __syncthreads();
#pragma unroll
  for (int i = 0; i < 4; i++)
    out[(size_t)(c0 + ty + i * 8) * R + r0 + tx] = (__bf16)t[tx][ty + i * 8];
}

// ---------------------------------------------------------------------------
// V transpose: qkv -> vt [B*NKV][HD][S], with pair-interleave permutation
// pi(16a+r) = 32*(a>>1) + 2r + (a&1) applied WITHIN each 64-kv tile.
// ---------------------------------------------------------------------------
__global__ __launch_bounds__(256) void tvt_kernel(const __bf16* __restrict__ qkv,
                                                  __bf16* __restrict__ vt) {
  __shared__ __bf16 t[32][33];
  int tx = threadIdx.x, ty = threadIdx.y;
  int z = blockIdx.z;
  int b = z >> 3, kvh = z & 7;
  int kv0 = blockIdx.y * 32, d0 = blockIdx.x * 32;
#pragma unroll
  for (int i = 0; i < 4; i++)
    t[ty + i * 8][tx] =
        qkv[(size_t)(b * S_LEN + kv0 + ty + i * 8) * QKVW + 5120 + kvh * HD + d0 + tx];
  __syncthreads();
  int cperm = kv0 + 2 * (tx & 15) + (tx >> 4);
#pragma unroll
  for (int i = 0; i < 4; i++)
    vt[((size_t)z * HD + d0 + ty + i * 8) * S_LEN + cperm] = t[tx][ty + i * 8];
}

// ---------------------------------------------------------------------------
// 256x256 GEMM, deep-pipelined (R13/R14 version, unchanged).
// ---------------------------------------------------------------------------
template<typename CT>
__global__ __launch_bounds__(512, 2) void gemm256(const __bf16* __restrict__ A,
                                                  const __bf16* __restrict__ Bt,
                                                  CT* __restrict__ C,
                                                  int K, int ldc, int nbx) {
  __shared__ char lds[131072];
  const int tid = threadIdx.x;
  const int l = tid & 63, w = tid >> 6;
  const int lrow = l & 15, lg = l >> 4;
  const int sw = (lrow & 7) << 4;

  int nwg = gridDim.x;
  int swz = (blockIdx.x & 7) * (nwg >> 3) + (blockIdx.x >> 3);
  int bx = swz % nbx, by = swz / nbx;
  int m0 = by * 256, n0 = bx * 256;

  const int rA = w * 8 + (l >> 3);
  const int csw = ((l & 7) ^ (l >> 3)) * 8;  // inverse-swizzled source col
  const __bf16* As_[2][2];
  const __bf16* Bs_[2][2];
#pragma unroll
  for (int h = 0; h < 2; h++)
#pragma unroll
    for (int p = 0; p < 2; p++) {
      As_[h][p] = A + (size_t)(m0 + h * 128 + p * 64 + rA) * K + csw;
      Bs_[h][p] = Bt + (size_t)(n0 + h * 128 + p * 64 + rA) * K + csw;
    }

  auto stageA = [&](int par, int h, int kt) {
#pragma unroll
    for (int p = 0; p < 2; p++)
      gload16(As_[h][p] + kt * 64,
              (const __bf16*)(lds + par * 32768 + h * 16384 + p * 8192 + w * 1024));
  };
  auto stageB = [&](int par, int h, int kt) {
#pragma unroll
    for (int p = 0; p < 2; p++)
      gload16(Bs_[h][p] + kt * 64,
              (const __bf16*)(lds + 65536 + par * 32768 + h * 16384 + p * 8192 + w * 1024));
  };

  const int arbase = (w >> 2) * 64 + lrow;
  const int brbase = (w & 3) * 32 + lrow;

  bf16x8 aA[4][2];
  bf16x8 bB[2][2][2];

  auto readA = [&](int par, int ah) {
#pragma unroll
    for (int i = 0; i < 4; i++)
#pragma unroll
      for (int kk = 0; kk < 2; kk++)
        aA[i][kk] = *reinterpret_cast<const bf16x8*>(
            lds + par * 32768 + (arbase + i * 16 + ah * 128) * 128 +
            ((kk * 64 + lg * 16) ^ sw));
  };
  auto readB = [&](int par, int bh) {
#pragma unroll
    for (int j = 0; j < 2; j++)
#pragma unroll
      for (int kk = 0; kk < 2; kk++)
        bB[bh][j][kk] = *reinterpret_cast<const bf16x8*>(
            lds + 65536 + par * 32768 + (brbase + j * 16 + bh * 128) * 128 +
            ((kk * 64 + lg * 16) ^ sw));
  };

  f32x4 acc[8][4];
#pragma unroll
  for (int i = 0; i < 8; i++)
#pragma unroll
    for (int j = 0; j < 4; j++) {
      acc[i][j][0] = 0.f; acc[i][j][1] = 0.f; acc[i][j][2] = 0.f; acc[i][j][3] = 0.f;
    }

  const int NT = K >> 6;

  stageA(0, 0, 0); stageB(0, 0, 0);
  stageA(0, 1, 0); stageB(0, 1, 0);
  stageA(1, 0, 1); stageB(1, 0, 1);
  VMCNT8();
  SBAR();

#define MFMA_QUAD(AH, BH)                                                   \
  __builtin_amdgcn_s_setprio(1);                                            \
  _Pragma("unroll") for (int i4 = 0; i4 < 4; i4++)                          \
      _Pragma("unroll") for (int j2 = 0; j2 < 2; j2++)                      \
          _Pragma("unroll") for (int kk = 0; kk < 2; kk++)                  \
              acc[(AH)*4 + i4][(BH)*2 + j2] =                               \
                  mfma16(aA[i4][kk], bB[BH][j2][kk], acc[(AH)*4 + i4][(BH)*2 + j2]); \
  __builtin_amdgcn_s_setprio(0);

#define GTILE256(PAR, TT)                                                   \
  {                                                                         \
    const int t1n = ((TT) + 1 < NT) ? (TT) + 1 : 0;                         \
    const int t2n = ((TT) + 2 < NT) ? (TT) + 2 : 0;                         \
    readA(PAR, 0);                                                          \
    readB(PAR, 0);                                                          \
    stageA(PAR ^ 1, 1, t1n);                                                \
    stageB(PAR ^ 1, 1, t1n);                                                \
    VMCNT8();                                                               \
    SBAR();                                                                 \
    MFMA_QUAD(0, 0);                                                        \
    SBAR();                                                                 \
    readB(PAR, 1);                                                          \
    stageA(PAR, 0, t2n);                                                    \
    SBAR();                                                                 \
    MFMA_QUAD(0, 1);                                                        \
    SBAR();                                                                 \
    readA(PAR, 1);                                                          \
    stageB(PAR, 0, t2n);                                                    \
    SBAR();                                                                 \
    MFMA_QUAD(1, 0);                                                        \
    MFMA_QUAD(1, 1);                                                        \
    VMCNT8();                                                               \
    SBAR();                                                                 \
  }

  for (int t = 0; t < NT; t += 2) {
    GTILE256(0, t);
    GTILE256(1, t + 1);
  }
#undef GTILE256
#undef MFMA_QUAD

#pragma unroll
  for (int i = 0; i < 8; i++) {
    int row = m0 + (w >> 2) * 64 + (i & 3) * 16 + (i >> 2) * 128 + lg * 4;
#pragma unroll
    for (int j = 0; j < 4; j++) {
      int col = n0 + (w & 3) * 32 + (j & 1) * 16 + (j >> 1) * 128 + lrow;
#pragma unroll
      for (int jj = 0; jj < 4; jj++)
        C[(size_t)(row + jj) * ldc + col] = (CT)acc[i][j][jj];
    }
  }
}

// ---------------------------------------------------------------------------
// 256x128 GEMM, deep-pipelined (R13/R14 version, unchanged).
// ---------------------------------------------------------------------------
template<typename CT>
__global__ __launch_bounds__(512, 2) void gemm128(const __bf16* __restrict__ A,
                                                  const __bf16* __restrict__ Bt,
                                                  CT* __restrict__ C,
                                                  int K, int ldc, int nbx) {
  __shared__ char lds[98304];
  const int tid = threadIdx.x;
  const int l = tid & 63, w = tid >> 6;
  const int lrow = l & 15, lg = l >> 4;
  const int sw = (lrow & 7) << 4;

  int nwg = gridDim.x;
  int swz = (blockIdx.x & 7) * (nwg >> 3) + (blockIdx.x >> 3);
  int bx = swz % nbx, by = swz / nbx;
  int m0 = by * 256, n0 = bx * 128;

  const int rA = w * 8 + (l >> 3);
  const int csw = ((l & 7) ^ (l >> 3)) * 8;
  const __bf16* As_[2][2];
  const __bf16* Bs_[2];
#pragma unroll
  for (int h = 0; h < 2; h++)
#pragma unroll
    for (int p = 0; p < 2; p++)
      As_[h][p] = A + (size_t)(m0 + h * 128 + p * 64 + rA) * K + csw;
#pragma unroll
  for (int p = 0; p < 2; p++)
    Bs_[p] = Bt + (size_t)(n0 + p * 64 + rA) * K + csw;

  auto stageA = [&](int par, int h, int kt) {
#pragma unroll
    for (int p = 0; p < 2; p++)
      gload16(As_[h][p] + kt * 64,
              (const __bf16*)(lds + par * 32768 + h * 16384 + p * 8192 + w * 1024));
  };
  auto stageB = [&](int par, int kt) {
#pragma unroll
    for (int p = 0; p < 2; p++)
      gload16(Bs_[p] + kt * 64,
              (const __bf16*)(lds + 65536 + par * 16384 + p * 8192 + w * 1024));
  };

  const int arbase = (w >> 2) * 64 + lrow;
  const int brbase = (w & 3) * 32 + lrow;

  bf16x8 aA[4][2];
  bf16x8 bB[2][2];

  auto readA = [&](int par, int ah) {
#pragma unroll
    for (int i = 0; i < 4; i++)
#pragma unroll
      for (int kk = 0; kk < 2; kk++)
        aA[i][kk] = *reinterpret_cast<const bf16x8*>(
            lds + par * 32768 + (arbase + i * 16 + ah * 128) * 128 +
            ((kk * 64 + lg * 16) ^ sw));
  };
  auto readB = [&](int par) {
#pragma unroll
    for (int j = 0; j < 2; j++)
#pragma unroll
      for (int kk = 0; kk < 2; kk++)
        bB[j][kk] = *reinterpret_cast<const bf16x8*>(
            lds + 65536 + par * 16384 + (brbase + j * 16) * 128 +
            ((kk * 64 + lg * 16) ^ sw));
  };

  f32x4 acc[8][2];
#pragma unroll
  for (int i = 0; i < 8; i++)
#pragma unroll
    for (int j = 0; j < 2; j++) {
      acc[i][j][0] = 0.f; acc[i][j][1] = 0.f; acc[i][j][2] = 0.f; acc[i][j][3] = 0.f;
    }

  const int NT = K >> 6;

  stageA(0, 0, 0); stageB(0, 0);
  stageA(0, 1, 0); stageB(1, 1); stageA(1, 0, 1);
  VMCNT6();
  SBAR();

#define MFMA_HALF(AH)                                                        \
  __builtin_amdgcn_s_setprio(1);                                             \
  _Pragma("unroll") for (int i4 = 0; i4 < 4; i4++)                           \
      _Pragma("unroll") for (int j2 = 0; j2 < 2; j2++)                       \
          _Pragma("unroll") for (int kk = 0; kk < 2; kk++)                   \
              acc[(AH)*4 + i4][j2] =                                         \
                  mfma16(aA[i4][kk], bB[j2][kk], acc[(AH)*4 + i4][j2]);      \
  __builtin_amdgcn_s_setprio(0);

#define GTILE128(PAR, TT)                                                    \
  {                                                                          \
    const int t1n = ((TT) + 1 < NT) ? (TT) + 1 : 0;                          \
    const int t2n = ((TT) + 2 < NT) ? (TT) + 2 : 0;                          \
    readA(PAR, 0);                                                           \
    readB(PAR);                                                              \
    stageA(PAR ^ 1, 1, t1n);                                                 \
    VMCNT6();                                                                \
    SBAR();                                                                  \
    MFMA_HALF(0);                                                            \
    SBAR();                                                                  \
    readA(PAR, 1);                                                           \
    stageB(PAR, t2n);                                                        \
    stageA(PAR, 0, t2n);                                                     \
    SBAR();                                                                  \
    MFMA_HALF(1);                                                            \
    VMCNT6();                                                                \
    SBAR();                                                                  \
  }

  for (int t = 0; t < NT; t += 2) {
    GTILE128(0, t);
    GTILE128(1, t + 1);
  }
#undef GTILE128
#undef MFMA_HALF

#pragma unroll
  for (int i = 0; i < 8; i++) {
    int row = m0 + (w >> 2) * 64 + (i & 3) * 16 + (i >> 2) * 128 + lg * 4;
#pragma unroll
    for (int j = 0; j < 2; j++) {
      int col = n0 + (w & 3) * 32 + j * 16 + lrow;
#pragma unroll
      for (int jj = 0; jj < 4; jj++)
        C[(size_t)(row + jj) * ldc + col] = (CT)acc[i][j][jj];
    }
  }
}

// ---------------------------------------------------------------------------
// K-only RoPE (Q-rope fused into attn). 4 rows per 256-thread block; within a
// row: 64 lanes = 8 kv-heads x 8 chunks.
// ---------------------------------------------------------------------------
__global__ __launch_bounds__(256) void ropek_kernel(__bf16* __restrict__ qkv,
                                                    const int* __restrict__ pos) {
  int row = blockIdx.x * 4 + (threadIdx.x >> 6);
  int t = threadIdx.x & 63;
  float p = (float)pos[row];
  int head = t >> 3, chunk = t & 7;
  __bf16* base = qkv + (size_t)row * QKVW + 4096 + head * HD + chunk * 8;
  bf16x8 x1 = *reinterpret_cast<const bf16x8*>(base);
  bf16x8 x2 = *reinterpret_cast<const bf16x8*>(base + 64);
  bf16x8 o1, o2;
#pragma unroll
  for (int e = 0; e < 8; e++) {
    float ang = p * exp2f(-0.20762050f * (float)(chunk * 8 + e));
    float s, c;
    __sincosf(ang, &s, &c);
    float a = (float)x1[e], b2 = (float)x2[e];
    o1[e] = (__bf16)(a * c - b2 * s);
    o2[e] = (__bf16)(b2 * c + a * s);
  }
  *reinterpret_cast<bf16x8*>(base) = o1;
  *reinterpret_cast<bf16x8*>(base + 64) = o2;
}

// ---------------------------------------------------------------------------
// Flash attention, causal, GQA (R13 structure) + fused Q-RoPE in the
// once-per-block Q prologue: per lane the RoPE pair (d, d+64) is (kk, kk+2)
// at the same e, so rotation is in-lane; SCL folded into cos/sin.
// ---------------------------------------------------------------------------
__global__ __launch_bounds__(512) void attn_kernel(const __bf16* __restrict__ qkv,
                                                   const __bf16* __restrict__ vt,
                                                   const int* __restrict__ pos,
                                                   __bf16* __restrict__ out) {
  __shared__ __bf16 Ks[64 * 128];      // [kv][d], swizzled, 16 KB
  __shared__ __bf16 Vs[128 * 64];      // [d][kv'], swizzled, 16 KB

  int tid = threadIdx.x;
  int l = tid & 63, w = tid >> 6;
  int bid = blockIdx.x;
  int qblk = 7 - (bid >> 6);           // heavy blocks first
  int rem = bid & 63;
  int h = rem & 31, b = rem >> 5;
  int kvh = h >> 2;
  int q0w = qblk * 256 + w * 32;
  int lrow = l & 15, lg = l >> 4;
  int sw = (lrow & 7) << 4;
  const float SCL = 0.08838834764831845f * 1.4426950408889634f;  // 1/sqrt(128)*log2e

  const __bf16* kbase = qkv + (size_t)(b * S_LEN) * QKVW + 4096 + kvh * HD;
  const __bf16* vbase = vt + ((size_t)(b * NKV + kvh) * HD) * S_LEN;

  int krow = tid >> 3;
  int kslot = (tid & 7) * 2;
  int vrow = tid >> 2;
  int vslot = (tid & 3) * 2;
  char* KsB = (char*)Ks;
  char* VsB = (char*)Vs;
  int koff0 = krow * 256 + ((kslot * 16) ^ ((krow & 7) << 4));
  int koff1 = krow * 256 + (((kslot + 1) * 16) ^ ((krow & 7) << 4));
  int voff0 = vrow * 128 + ((vslot * 16) ^ ((vrow & 7) << 4));
  int voff1 = vrow * 128 + (((vslot + 1) * 16) ^ ((vrow & 7) << 4));
  const __bf16* kg = kbase + (size_t)krow * QKVW + kslot * 8;
  const __bf16* vg = vbase + (size_t)vrow * S_LEN + vslot * 8;

  // Q fragments: load raw Q, apply RoPE in-register (pairs are in-lane:
  // d = kk*32 + lg*8 + e < 64 pairs with d+64 held at kk+2), scale by SCL.
  bf16x8 qf[2][4];
#pragma unroll
  for (int mi = 0; mi < 2; mi++) {
    int qrow = q0w + mi * 16 + lrow;
    const __bf16* qp = qkv + (size_t)(b * S_LEN + qrow) * QKVW + h * HD + lg * 8;
    float p = (float)pos[b * S_LEN + qrow];
#pragma unroll
    for (int kk = 0; kk < 2; kk++) {
      bf16x8 xlo = *reinterpret_cast<const bf16x8*>(qp + kk * 32);
      bf16x8 xhi = *reinterpret_cast<const bf16x8*>(qp + (kk + 2) * 32);
      bf16x8 olo, ohi;
#pragma unroll
      for (int e = 0; e < 8; e++) {
        int d = kk * 32 + lg * 8 + e;              // 0..63
        float ang = p * exp2f(-0.20762050f * (float)d);
        float s, c;
        __sincosf(ang, &s, &c);
        c *= SCL; s *= SCL;
        float a = (float)xlo[e], b2 = (float)xhi[e];
        olo[e] = (__bf16)(a * c - b2 * s);
        ohi[e] = (__bf16)(b2 * c + a * s);
      }
      qf[mi][kk] = olo;
      qf[mi][kk + 2] = ohi;
    }
  }

  f32x4 ov[2][8];
#pragma unroll
  for (int mi = 0; mi < 2; mi++)
#pragma unroll
    for (int n = 0; n < 8; n++) {
      ov[mi][n][0] = 0.f; ov[mi][n][1] = 0.f; ov[mi][n][2] = 0.f; ov[mi][n][3] = 0.f;
    }
  float m[2], ssum[2];
  m[0] = -3.0e38f; m[1] = -3.0e38f;
  ssum[0] = 0.f; ssum[1] = 0.f;

  int nt = 4 * qblk + 4;
  bf16x8 kr0, kr1, vr0, vr1;

  kr0 = *reinterpret_cast<const bf16x8*>(kg);
  kr1 = *reinterpret_cast<const bf16x8*>(kg + 8);
  vr0 = *reinterpret_cast<const bf16x8*>(vg);
  vr1 = *reinterpret_cast<const bf16x8*>(vg + 8);
  *reinterpret_cast<bf16x8*>(KsB + koff0) = kr0;
  *reinterpret_cast<bf16x8*>(KsB + koff1) = kr1;
  *reinterpret_cast<bf16x8*>(VsB + voff0) = vr0;
  *reinterpret_cast<bf16x8*>(VsB + voff1) = vr1;
  __syncthreads();

  for (int t = 0;; t++) {
    int kv0 = t * 64;
    bool more = (t + 1 < nt);
    if (more) {
      int kvn = kv0 + 64;
      kr0 = *reinterpret_cast<const bf16x8*>(kg + (size_t)kvn * QKVW);
      kr1 = *reinterpret_cast<const bf16x8*>(kg + (size_t)kvn * QKVW + 8);
      vr0 = *reinterpret_cast<const bf16x8*>(vg + kvn);
      vr1 = *reinterpret_cast<const bf16x8*>(vg + kvn + 8);
    }

    bool active = (kv0 <= q0w + 31);
    if (active) {
      // ---- swapped QK^T: sc[mi][c] = S^T tile (rows=kv, cols=q)
      f32x4 sc[2][4];
#pragma unroll
      for (int mi = 0; mi < 2; mi++)
#pragma unroll
        for (int c = 0; c < 4; c++) {
          sc[mi][c][0] = 0.f; sc[mi][c][1] = 0.f; sc[mi][c][2] = 0.f; sc[mi][c][3] = 0.f;
        }
#pragma unroll
      for (int c = 0; c < 4; c++) {
        int rb = (c * 16 + lrow) * 256;
#pragma unroll
        for (int kk = 0; kk < 4; kk++) {
          bf16x8 kf = *reinterpret_cast<const bf16x8*>(KsB + rb + ((kk * 64 + lg * 16) ^ sw));
          sc[0][c] = mfma16(kf, qf[0][kk], sc[0][c]);
          sc[1][c] = mfma16(kf, qf[1][kk], sc[1][c]);
        }
      }

      // ---- causal mask: kv = kv0 + c*16 + lg*4 + jj ; q = q0w + mi*16 + lrow
      bool bound = (kv0 + 64 > q0w);
      if (bound) {
#pragma unroll
        for (int mi = 0; mi < 2; mi++) {
          int qidx = q0w + mi * 16 + lrow;
#pragma unroll
          for (int jj = 0; jj < 4; jj++) {
            int kvb = kv0 + lg * 4 + jj;
            if (kvb > qidx)      sc[mi][0][jj] = -3.0e38f;
            if (kvb + 16 > qidx) sc[mi][1][jj] = -3.0e38f;
            if (kvb + 32 > qidx) sc[mi][2][jj] = -3.0e38f;
            if (kvb + 48 > qidx) sc[mi][3][jj] = -3.0e38f;
          }
        }
      }

      // ---- per-lane growth check (all 16 values in-lane belong to q=lrow)
      float lm[2];
      bool lanegrow = false;
#pragma unroll
      for (int mi = 0; mi < 2; mi++) {
        float a0 = fmaxf(fmaxf(sc[mi][0][0], sc[mi][0][1]), fmaxf(sc[mi][0][2], sc[mi][0][3]));
        float a1 = fmaxf(fmaxf(sc[mi][1][0], sc[mi][1][1]), fmaxf(sc[mi][1][2], sc[mi][1][3]));
        float a2 = fmaxf(fmaxf(sc[mi][2][0], sc[mi][2][1]), fmaxf(sc[mi][2][2], sc[mi][2][3]));
        float a3 = fmaxf(fmaxf(sc[mi][3][0], sc[mi][3][1]), fmaxf(sc[mi][3][2], sc[mi][3][3]));
        lm[mi] = fmaxf(fmaxf(a0, a1), fmaxf(a2, a3));
        lanegrow |= (lm[mi] > m[mi] + 8.0f);
      }

      if (__any(lanegrow)) {
        // rare slow path: reduce row max over the 4 lg lanes, rescale
        float es[2];
#pragma unroll
        for (int mi = 0; mi < 2; mi++) {
          float r = lm[mi];
          r = fmaxf(r, __shfl_xor(r, 16));
          r = fmaxf(r, __shfl_xor(r, 32));
          float mo = m[mi];
          bool grow = (r > mo + 8.0f);
          float mn = grow ? r : mo;
          float e = grow ? exp2f(mo - r) : 1.0f;
          es[mi] = e;
          m[mi] = mn;
          ssum[mi] *= e;
        }
        float esv[2][4];
#pragma unroll
        for (int mi = 0; mi < 2; mi++)
#pragma unroll
          for (int jj = 0; jj < 4; jj++)
            esv[mi][jj] = __shfl(es[mi], lg * 4 + jj);
#pragma unroll
        for (int mi = 0; mi < 2; mi++)
#pragma unroll
          for (int n = 0; n < 8; n++)
#pragma unroll
            for (int jj = 0; jj < 4; jj++) ov[mi][n][jj] *= esv[mi][jj];
      }

      // ---- exp2 + in-register P pack (pi order): pa[mi][c>>1][(r<<1)|(c&1)]
      bf16x8 pa[2][2];
#pragma unroll
      for (int mi = 0; mi < 2; mi++) {
        float mn = m[mi];
#pragma unroll
        for (int c = 0; c < 4; c++)
#pragma unroll
          for (int r = 0; r < 4; r++) {
            float p = exp2f(sc[mi][c][r] - mn);
            ssum[mi] += p;
            pa[mi][c >> 1][(r << 1) | (c & 1)] = (__bf16)p;
          }
      }

      // ---- PV: A = pa (in-register), B = pi-permuted V^T from LDS
#pragma unroll
      for (int kvs = 0; kvs < 2; kvs++) {
#pragma unroll
        for (int n = 0; n < 8; n++) {
          bf16x8 vf = *reinterpret_cast<const bf16x8*>(
              VsB + (n * 16 + lrow) * 128 + ((kvs * 64 + lg * 16) ^ sw));
          ov[0][n] = mfma16(pa[0][kvs], vf, ov[0][n]);
          ov[1][n] = mfma16(pa[1][kvs], vf, ov[1][n]);
        }
      }
    }

    if (!more) break;
    __syncthreads();
    *reinterpret_cast<bf16x8*>(KsB + koff0) = kr0;
    *reinterpret_cast<bf16x8*>(KsB + koff1) = kr1;
    *reinterpret_cast<bf16x8*>(VsB + voff0) = vr0;
    *reinterpret_cast<bf16x8*>(VsB + voff1) = vr1;
    __syncthreads();
  }

  // ---- epilogue: reduce ssum over lg, redistribute to ov's q-mapping, store
  float rs[2];
#pragma unroll
  for (int mi = 0; mi < 2; mi++) {
    float s = ssum[mi];
    s += __shfl_xor(s, 16);
    s += __shfl_xor(s, 32);
    rs[mi] = s;
  }
  float rinv[2][4];
#pragma unroll
  for (int mi = 0; mi < 2; mi++)
#pragma unroll
    for (int jj = 0; jj < 4; jj++)
      rinv[mi][jj] = 1.0f / __shfl(rs[mi], lg * 4 + jj);
#pragma unroll
  for (int mi = 0; mi < 2; mi++)
#pragma unroll
    for (int n = 0; n < 8; n++)
#pragma unroll
      for (int jj = 0; jj < 4; jj++) {
        out[(size_t)(b * S_LEN + q0w + mi * 16 + lg * 4 + jj) * HIDDEN + h * HD + n * 16 + lrow] =
            (__bf16)(ov[mi][n][jj] * rinv[mi][jj]);
      }
}

// ---------------------------------------------------------------------------
// Workspace layout (bytes), total 142606336:
//   h_bf / a_buf (aliased) @ 0          33554432   bf16 [4096][4096]
//   Wt (qkv^T, later Wo^T) @ 33554432   50331648   bf16 [6144][4096]
//   qkv_buf                @ 83886080   50331648   bf16 [4096][6144]
//   vt_buf                 @ 134217728   8388608   bf16 [16][128][2048]
// ---------------------------------------------------------------------------
extern "C" void kernel_launch(void* const* d_in, const int* in_sizes, int n_in,
                              void* d_out, int out_size, void* d_ws, size_t ws_size,
                              hipStream_t stream) {
  const float* hidden = (const float*)d_in[0];
  const int* posids   = (const int*)d_in[1];
  const float* Wq     = (const float*)d_in[2];
  const float* Wk     = (const float*)d_in[3];
  const float* Wv     = (const float*)d_in[4];
  const float* Wo     = (const float*)d_in[5];
  float* out = (float*)d_out;

  char* ws = (char*)d_ws;
  __bf16* h_bf    = (__bf16*)(ws + 0);
  __bf16* a_buf   = h_bf;  // aliased: h last read by QKV GEMMs, before attn writes
  __bf16* Wt      = (__bf16*)(ws + 33554432);
  __bf16* qkv_buf = (__bf16*)(ws + 83886080);
  __bf16* vt_buf  = (__bf16*)(ws + 134217728);

  dim3 b256(256), b328(32, 8), b512(512);

  // 1. hidden -> bf16
  cvt_kernel<<<dim3(MROWS * HIDDEN / (256 * 8)), b256, 0, stream>>>(hidden, h_bf, MROWS * HIDDEN);

  // 2. fused weight transpose: Wt = [Wq^T ; Wk^T ; Wv^T]  [6144][4096]
  tcvt3_kernel<<<dim3(128, 128, 3), b328, 0, stream>>>(Wq, Wk, Wv, Wt);

  // 3a. QKV main: cols [0,4096) via 256^2 tiles -> 256 blocks (1 round)
  gemm256<__bf16><<<dim3(256), b512, 0, stream>>>(
      h_bf, Wt, qkv_buf, HIDDEN, QKVW, 4096 / 256);
  // 3b. QKV tail: cols [4096,6144) via 256x128 tiles -> 256 blocks
  gemm128<__bf16><<<dim3(256), b512, 0, stream>>>(
      h_bf, Wt + (size_t)4096 * 4096, qkv_buf + 4096, HIDDEN, QKVW, 2048 / 128);

  // 4. RoPE on K only (Q-rope fused into attn prologue)
  ropek_kernel<<<dim3(MROWS / 4), b256, 0, stream>>>(qkv_buf, posids);

  // 5. V^T (pi-permuted kv within each 64-tile)
  tvt_kernel<<<dim3(HD / 32, S_LEN / 32, BATCH * NKV), b328, 0, stream>>>(qkv_buf, vt_buf);

  // 6. attention -> a_buf  (512 blocks, heavy-first)
  attn_kernel<<<dim3(8 * NH * BATCH), b512, 0, stream>>>(qkv_buf, vt_buf, posids, a_buf);

  // 7. Wo^T (reuse Wt)
  tcvt_f32<<<dim3(HIDDEN / 32, HIDDEN / 32), b328, 0, stream>>>(Wo, Wt, HIDDEN, HIDDEN);

  // 8. out = a @ Wo  (fp32 out; 256 blocks = 1 balanced round)
  gemm256<float><<<dim3(256), b512, 0, stream>>>(
      a_buf, Wt, out, HIDDEN, HIDDEN, HIDDEN / 256);
}